// Round 13
// baseline (920.293 us; speedup 1.0000x reference)
//
#include <hip/hip_runtime.h>
#include <hip/hip_bf16.h>

#define N_NODES 50000
#define N_EDGES 800000
#define N_GRAPHS 32
#define NODE_DIM 128
#define HIDDEN 256
#define N_LAYERS 3

typedef __attribute__((ext_vector_type(8))) short bh8;   // 8 bf16 (4 VGPRs)
typedef __attribute__((ext_vector_type(4))) short bh4;   // 4 bf16 (8B)
typedef __attribute__((ext_vector_type(4))) float f32x4; // MFMA acc

#define MP 264  // M/H tile pitch (bf16)
#define YP 136  // X-tile pitch (bf16)
#define DQ 16   // dst nodes per edge-CSR block
#define YDP 264 // ydc LDS pitch (shorts)
#define WSP 36  // wsh pitch (floats)
#define SWP 40  // per-wave S-tile pitch (shorts): 80B rows -> 2-way-free b128 reads
#define STP 136 // epilogue agg staging pitch (shorts)
#define SCAN_BS 512
#define OB2 32  // out_stage2 blocks

// swish via hw rcp (avoids full-precision fp32 divide sequence)
__device__ __forceinline__ float swish_f(float v) {
    return v * __builtin_amdgcn_rcpf(1.0f + __expf(-v));
}

// round-half-up bf16 (2 int ops; differs from RNE only on exact ties)
__device__ __forceinline__ short f2bf(float f) {
    union { float f; unsigned u; } v;
    v.f = f;
    return (short)((v.u + 0x8000u) >> 16);
}

__device__ __forceinline__ float bf2f(short s) {
    union { unsigned u; float f; } v;
    v.u = ((unsigned)(unsigned short)s) << 16;
    return v.f;
}

// x[n][c] = embed[z[n]][c]; also bf16 mirror
__global__ void embed_kernel(const float* __restrict__ emb, const int* __restrict__ z,
                             float* __restrict__ x, short* __restrict__ xb) {
    int i = blockIdx.x * blockDim.x + threadIdx.x;
    int n = i >> 7, c = i & 127;
    float v = emb[z[n] * 128 + c];
    x[i] = v;
    xb[i] = f2bf(v);
}

// out[l][h][k] = bf16(in[l][k][h]) for k<K_in else 0
__global__ void cvt_wT_kernel(const float* __restrict__ in, short* __restrict__ out,
                              int K_in, int H, int K_pad, int total) {
    int i = blockIdx.x * blockDim.x + threadIdx.x;
    if (i >= total) return;
    int k = i % K_pad;
    int t = i / K_pad;
    int h = t % H;
    int l = t / H;
    out[i] = (k < K_in) ? f2bf(in[((size_t)l * K_in + k) * H + h]) : (short)0;
}

// combined edge-W1 transpose: out[l][m][k] bf16, m<256 -> W1[l][k][m] (dst part),
// m>=256 -> W1[l][128+k][m-256] (src part). K=128 exact.
__global__ void cvt_wc_kernel(const float* __restrict__ in, short* __restrict__ out, int total) {
    int i = blockIdx.x * blockDim.x + threadIdx.x;
    if (i >= total) return;
    int k = i & 127;
    int t = i >> 7;
    int m = t & 511;
    int l = t >> 9;
    size_t src;
    if (m < 256) src = ((size_t)l * 257 + k) * 256 + m;
    else src = ((size_t)l * 257 + 128 + k) * 256 + (m - 256);
    out[i] = f2bf(in[src]);
}

// ---- CSR counting-sort build ----
__global__ void hist_kernel(const int* __restrict__ eidx, int* __restrict__ deg) {
    int e = blockIdx.x * blockDim.x + threadIdx.x;
    if (e >= N_EDGES) return;
    atomicAdd(&deg[eidx[N_EDGES + e]], 1);
}

__global__ void scan1_kernel(const int* __restrict__ deg, int* __restrict__ sc,
                             int* __restrict__ bsum, int n) {
    __shared__ int s[SCAN_BS];
    int i = blockIdx.x * SCAN_BS + threadIdx.x;
    int v = (i < n) ? deg[i] : 0;
    s[threadIdx.x] = v;
    __syncthreads();
    for (int off = 1; off < SCAN_BS; off <<= 1) {
        int t = (threadIdx.x >= off) ? s[threadIdx.x - off] : 0;
        __syncthreads();
        s[threadIdx.x] += t;
        __syncthreads();
    }
    if (i < n) sc[i] = s[threadIdx.x];
    if (threadIdx.x == SCAN_BS - 1) bsum[blockIdx.x] = s[SCAN_BS - 1];
}

__global__ void scan2_kernel(int* __restrict__ bsum, int nb) {  // 1 block, 128 threads
    __shared__ int s[128];
    int v = (threadIdx.x < nb) ? bsum[threadIdx.x] : 0;
    s[threadIdx.x] = v;
    __syncthreads();
    for (int off = 1; off < 128; off <<= 1) {
        int t = (threadIdx.x >= off) ? s[threadIdx.x - off] : 0;
        __syncthreads();
        s[threadIdx.x] += t;
        __syncthreads();
    }
    if (threadIdx.x < nb) bsum[threadIdx.x] = s[threadIdx.x];
}

__global__ void scan3_kernel(const int* __restrict__ sc, const int* __restrict__ deg,
                             const int* __restrict__ bsum, int* __restrict__ rowptr,
                             int n, int total) {
    int i = blockIdx.x * SCAN_BS + threadIdx.x;
    if (i > n) return;
    if (i == n) { rowptr[n] = total; return; }
    int off = (blockIdx.x > 0) ? bsum[blockIdx.x - 1] : 0;
    rowptr[i] = sc[i] - deg[i] + off;
}

// scatter into dst-sorted order, packing (src, dst, d2); d2 computed inline
__global__ void fill_kernel(const float* __restrict__ pos, const float* __restrict__ shift,
                            const float* __restrict__ lattice, const int* __restrict__ eidx,
                            const int* __restrict__ batch, const int* __restrict__ rowptr,
                            int* __restrict__ fillc, int4* __restrict__ epack) {
    int e = blockIdx.x * blockDim.x + threadIdx.x;
    if (e >= N_EDGES) return;
    int s = eidx[e];
    int d = eidx[N_EDGES + e];
    int b = batch[s];
    const float* lat = lattice + b * 9;
    float s0 = shift[e * 3 + 0], s1 = shift[e * 3 + 1], s2 = shift[e * 3 + 2];
    float acc = 0.f;
#pragma unroll
    for (int j = 0; j < 3; j++) {
        float v = pos[d * 3 + j] - pos[s * 3 + j] + s0 * lat[j] + s1 * lat[3 + j] + s2 * lat[6 + j];
        acc += v * v;
    }
    int p = rowptr[d] + atomicAdd(&fillc[d], 1);
    epack[p] = make_int4(s, d, __float_as_int(acc), 0);
}

// ---------------- per-layer node-level GEMM1 precompute ----------------
__global__ __launch_bounds__(256, 4) void y_precompute(
    const short* __restrict__ xb, const short* __restrict__ WcT,
    const float* __restrict__ b1, short* __restrict__ ydb, short* __restrict__ ysb) {
    __shared__ __align__(16) short B[64 * MP];  // X [64][YP] then Y [64][MP]
    const int tid = threadIdx.x;
    const int half = blockIdx.x & 1;
    const int n0 = (blockIdx.x >> 1) * 64;
    const int wv = tid >> 6;
    const int ln = tid & 63;
    const int lr = ln & 15;
    const int lq = ln >> 4;

    {
        int row = tid >> 2, p = tid & 3;
        int gn = n0 + row;
        if (gn < N_NODES) {
            const int4* xp = (const int4*)(xb + (size_t)gn * 128) + p * 4;
#pragma unroll
            for (int i = 0; i < 4; i++) *(int4*)(B + row * YP + (p * 4 + i) * 8) = xp[i];
        } else {
            int4 z4 = make_int4(0, 0, 0, 0);
#pragma unroll
            for (int i = 0; i < 4; i++) *(int4*)(B + row * YP + (p * 4 + i) * 8) = z4;
        }
    }
    __syncthreads();

    f32x4 acc[4][4];
#pragma unroll
    for (int a = 0; a < 4; a++)
#pragma unroll
        for (int b = 0; b < 4; b++) acc[a][b] = (f32x4)(0.f);

    const short* a_base = WcT + (size_t)(half * 256 + wv * 64 + lr) * 128 + lq * 8;
#pragma unroll
    for (int ks = 0; ks < 128; ks += 32) {
        bh8 af[4], bf[4];
#pragma unroll
        for (int mt = 0; mt < 4; mt++) af[mt] = *(const bh8*)(a_base + mt * 16 * 128 + ks);
#pragma unroll
        for (int nt = 0; nt < 4; nt++)
            bf[nt] = *(const bh8*)(B + (nt * 16 + lr) * YP + ks + lq * 8);
#pragma unroll
        for (int mt = 0; mt < 4; mt++)
#pragma unroll
            for (int nt = 0; nt < 4; nt++)
                acc[mt][nt] = __builtin_amdgcn_mfma_f32_16x16x32_bf16(af[mt], bf[nt],
                                                                      acc[mt][nt], 0, 0, 0);
    }
    __syncthreads();   // done reading X -> B becomes Y [64][MP]

#pragma unroll
    for (int mt = 0; mt < 4; mt++) {
        int h0 = wv * 64 + mt * 16 + lq * 4;
        float4 bb = half ? make_float4(0.f, 0.f, 0.f, 0.f) : *(const float4*)(b1 + h0);
#pragma unroll
        for (int nt = 0; nt < 4; nt++) {
            bh4 pk;
            pk[0] = f2bf(acc[mt][nt][0] + bb.x);
            pk[1] = f2bf(acc[mt][nt][1] + bb.y);
            pk[2] = f2bf(acc[mt][nt][2] + bb.z);
            pk[3] = f2bf(acc[mt][nt][3] + bb.w);
            *(bh4*)(B + (nt * 16 + lr) * MP + h0) = pk;
        }
    }
    __syncthreads();

    // coalesced copy: instr i writes 64 consecutive int4 (1KB contiguous)
    short* outp = half ? ysb : ydb;
    int4* og = (int4*)(outp + (size_t)n0 * 256);
#pragma unroll
    for (int i = 0; i < 8; i++) {
        int f = i * 256 + tid;             // flat int4 index over [64][256]
        int row = f >> 5;
        if (n0 + row < N_NODES)
            og[f] = *(const int4*)(B + row * MP + (f & 31) * 8);
    }
}

// ---------------- Edge MLP, CSR dst-centric, MFMA segment aggregation ----------------
// r12 structure + LDS bank-conflict fix: 16B-slot XOR swizzle (q ^= p&3) on the
// stage-A MB stores + matching GEMM2 reads, and identically on ydc staging/reads.
// Mechanism: raw addresses bank = 4*el + 16*(p&1) + 4q lose p's bits 1-2 (p*16dw
// wraps mod 32 banks) -> lanes p,p+2,p+4,p+6 collide 4-way on every stage-A store.
// The XOR re-injects p bits 1-2 -> 2-way (free, m136). Both-sides-or-neither.
__global__ __launch_bounds__(256, 3) void edge_mlp_csr(
    const short* __restrict__ ydb, const short* __restrict__ ysb,
    const float* __restrict__ w1c,   // [256] f32: W1 row 256 (the d2 row)
    const int4* __restrict__ epack,  // dst-sorted (src, dst, d2)
    const int* __restrict__ rowptr,
    const short* __restrict__ W2T,   // [128][256] bf16
    const float* __restrict__ b2,
    short* __restrict__ aggb) {
    __shared__ __align__(16) short MB[32 * MP];     // 16896B: M tile (slot-swizzled)
    __shared__ __align__(16) short Stw[4 * 32 * SWP]; // 10240B: per-wave S tiles / agg staging
    __shared__ __align__(16) short ydc[DQ * YDP];   // 8448B (slot-swizzled)
    __shared__ __align__(16) float wsh[8 * WSP];    // 1152B
    __shared__ int s_dl[32];
    const int tid = threadIdx.x;
    const int n0 = blockIdx.x * DQ;
    const int wv = tid >> 6;
    const int ln = tid & 63;
    const int lr = ln & 15;
    const int lq = ln >> 4;
    const int el = tid >> 3;
    const int p = tid & 7;

    const int estart = rowptr[n0];
    const int eend = rowptr[n0 + DQ];

    // ---- phase 0: stage yd rows (coalesced, slot-swizzled), w1c -> wsh ----
    {
        const int4* src = (const int4*)(ydb + (size_t)n0 * 256);  // 512 int4 contiguous
        int4* dst = (int4*)ydc;
#pragma unroll
        for (int i = 0; i < 2; i++) {
            int f = tid + i * 256;
            int s = f & 31;                                  // logical int4 slot in row
            int sp = (s & ~3) | ((s & 3) ^ ((s >> 2) & 3));  // swizzled slot
            dst[(f >> 5) * 33 + sp] = src[f];                // YDP=264 shorts = 33 int4
        }
        wsh[(tid >> 5) * WSP + (tid & 31)] = w1c[tid];
    }
    __syncthreads();

    f32x4 acc2[2];
    acc2[0] = (f32x4)(0.f);
    acc2[1] = (f32x4)(0.f);
    short* Sw = Stw + wv * 32 * SWP;   // wave-private [32 ch][SWP] bf16

    const int nch = (eend - estart + 31) >> 5;
    for (int ch = 0; ch < nch; ch++) {
        const int e0 = estart + ch * 32;

        // ---- stage A: gather ys[src] + ydc[dl] + d2*wsh -> swish -> M (8 thr/edge) ----
        {
            int e = e0 + el;
            bool valid = e < eend;
            int s = 0, dl = -1;
            float d2v = 0.f;
            if (valid) {
                int4 ep = epack[e];
                s = ep.x;
                dl = ep.y - n0;
                d2v = __int_as_float(ep.z);
            }
            if (p == 0) s_dl[el] = dl;
            if (valid) {
                const int4* ys = (const int4*)(ysb + (size_t)s * 256) + p * 4;
                const short* yl = ydc + dl * YDP + p * 32;
                const float* wl = wsh + p * WSP;
#pragma unroll
                for (int h = 0; h < 2; h++) {
                    int4 bv0 = ys[h * 2];
                    int4 bv1 = ys[h * 2 + 1];
#pragma unroll
                    for (int qq = 0; qq < 2; qq++) {
                        int q = h * 2 + qq;
                        int qsw = (q ^ (p & 3)) * 8;   // swizzled 16B slot
                        union { int4 v; short s2[8]; } b, m;
                        b.v = qq ? bv1 : bv0;
                        bh8 av = *(const bh8*)(yl + qsw);
                        float4 w0 = *(const float4*)(wl + q * 8);
                        float4 w1 = *(const float4*)(wl + q * 8 + 4);
                        m.s2[0] = f2bf(swish_f(bf2f(av[0]) + bf2f(b.s2[0]) + d2v * w0.x));
                        m.s2[1] = f2bf(swish_f(bf2f(av[1]) + bf2f(b.s2[1]) + d2v * w0.y));
                        m.s2[2] = f2bf(swish_f(bf2f(av[2]) + bf2f(b.s2[2]) + d2v * w0.z));
                        m.s2[3] = f2bf(swish_f(bf2f(av[3]) + bf2f(b.s2[3]) + d2v * w0.w));
                        m.s2[4] = f2bf(swish_f(bf2f(av[4]) + bf2f(b.s2[4]) + d2v * w1.x));
                        m.s2[5] = f2bf(swish_f(bf2f(av[5]) + bf2f(b.s2[5]) + d2v * w1.y));
                        m.s2[6] = f2bf(swish_f(bf2f(av[6]) + bf2f(b.s2[6]) + d2v * w1.z));
                        m.s2[7] = f2bf(swish_f(bf2f(av[7]) + bf2f(b.s2[7]) + d2v * w1.w));
                        *(int4*)(MB + el * MP + p * 32 + qsw) = m.v;
                    }
                }
            } else {
                int4 z4 = make_int4(0, 0, 0, 0);
#pragma unroll
                for (int q = 0; q < 4; q++) *(int4*)(MB + el * MP + p * 32 + q * 8) = z4;
            }
        }
        __syncthreads();   // (A) M + s_dl ready

        // NOTE on swizzle consistency: logical M column (ch-slot) S = ks/8 + lq with
        // p_s = S>>2 = ks>>5, q_s = S&3 = lq; stored at q_s ^ (p_s&3).
        // ---- GEMM2: 128 ch x 32 edges, each wave 32 ch; S -> wave-private bf16 tile ----
        {
            f32x4 acc[2][2];
#pragma unroll
            for (int a = 0; a < 2; a++)
#pragma unroll
                for (int b = 0; b < 2; b++) acc[a][b] = (f32x4)(0.f);

            const short* a_base = W2T + (size_t)(wv * 32 + lr) * 256 + lq * 8;
            for (int ks = 0; ks < 256; ks += 32) {
                int qx = (lq ^ ((ks >> 5) & 3)) * 8;   // unswizzle read slot
                bh8 af[2], bf[2];
#pragma unroll
                for (int mt = 0; mt < 2; mt++) af[mt] = *(const bh8*)(a_base + mt * 16 * 256 + ks);
#pragma unroll
                for (int nt = 0; nt < 2; nt++)
                    bf[nt] = *(const bh8*)(MB + (nt * 16 + lr) * MP + ks + qx);
#pragma unroll
                for (int mt = 0; mt < 2; mt++)
#pragma unroll
                    for (int nt = 0; nt < 2; nt++)
                        acc[mt][nt] = __builtin_amdgcn_mfma_f32_16x16x32_bf16(af[mt], bf[nt],
                                                                              acc[mt][nt], 0, 0, 0);
            }
            // swish2 + bf16 -> Sw[row=ch (32), col=e (32)]  (wave-private, no barrier)
#pragma unroll
            for (int mt = 0; mt < 2; mt++) {
                int r0 = mt * 16 + lq * 4;
                float4 bb = *(const float4*)(b2 + wv * 32 + r0);
#pragma unroll
                for (int nt = 0; nt < 2; nt++) {
                    int e = nt * 16 + lr;
                    Sw[(r0 + 0) * SWP + e] = f2bf(swish_f(acc[mt][nt][0] + bb.x));
                    Sw[(r0 + 1) * SWP + e] = f2bf(swish_f(acc[mt][nt][1] + bb.y));
                    Sw[(r0 + 2) * SWP + e] = f2bf(swish_f(acc[mt][nt][2] + bb.z));
                    Sw[(r0 + 3) * SWP + e] = f2bf(swish_f(acc[mt][nt][3] + bb.w));
                }
            }
        }

        // ---- seg-MFMA aggregation: acc2[mt] += Seg @ S  ----
        {
            bh8 af;
#pragma unroll
            for (int j = 0; j < 8; j++)
                af[j] = (s_dl[lq * 8 + j] == lr) ? (short)0x3F80 : (short)0;
#pragma unroll
            for (int mt = 0; mt < 2; mt++) {
                bh8 bfv = *(const bh8*)(Sw + (mt * 16 + lr) * SWP + lq * 8);
                acc2[mt] = __builtin_amdgcn_mfma_f32_16x16x32_bf16(af, bfv, acc2[mt], 0, 0, 0);
            }
        }
        __syncthreads();   // (B) M-reads + s_dl-reads done before next stageA
    }

    // ---- epilogue: acc2 (C layout: row dl=(lq*4+j), col ch=lr) -> LDS -> coalesced bf16 ----
#pragma unroll
    for (int mt = 0; mt < 2; mt++)
#pragma unroll
        for (int j = 0; j < 4; j++)
            Stw[(lq * 4 + j) * STP + wv * 32 + mt * 16 + lr] = f2bf(acc2[mt][j]);
    __syncthreads();
    {
        int row = tid >> 4, c16 = tid & 15;
        *(int4*)(aggb + ((size_t)(n0 + row)) * 128 + c16 * 8) =
            *(const int4*)(Stw + row * STP + c16 * 8);
    }
}

// ---------------- Node MLP (MFMA, single LDS buffer, 4 blocks/CU) ----------------
__global__ __launch_bounds__(256, 4) void node_mlp_mfma(
    float* __restrict__ x, short* __restrict__ xb, const short* __restrict__ aggb,
    const short* __restrict__ W1T, const float* __restrict__ b1,
    const short* __restrict__ W2T, const float* __restrict__ b2) {
    __shared__ __align__(16) short X[64 * MP];
    const int tid = threadIdx.x;
    const int n0 = blockIdx.x * 64;
    const int wv = tid >> 6;
    const int ln = tid & 63;
    const int lr = ln & 15;
    const int lq = ln >> 4;

    {
        int row = tid >> 2, p = tid & 3;
        int gn = n0 + row;
        if (gn < N_NODES) {
            const int4* xp = (const int4*)(xb + (size_t)gn * 128);
            const int4* ap = (const int4*)(aggb + (size_t)gn * 128);
#pragma unroll
            for (int q = 0; q < 4; q++) {
                int c = p * 4 + q;
                *(int4*)(X + row * MP + c * 8) = xp[c];
                *(int4*)(X + row * MP + 128 + c * 8) = ap[c];
            }
        } else {
            int4 z4 = make_int4(0, 0, 0, 0);
#pragma unroll
            for (int q = 0; q < 8; q++) *(int4*)(X + row * MP + (p * 8 + q) * 8) = z4;
        }
    }
    __syncthreads();

    bh4 hv[4][4];
    {
        f32x4 acc[4][4];
#pragma unroll
        for (int a = 0; a < 4; a++)
#pragma unroll
            for (int b = 0; b < 4; b++) acc[a][b] = (f32x4)(0.f);

        const short* a_base = W1T + (size_t)(wv * 64 + lr) * 256 + lq * 8;
        for (int ks = 0; ks < 256; ks += 32) {
            bh8 af[4], bf[4];
#pragma unroll
            for (int mt = 0; mt < 4; mt++) af[mt] = *(const bh8*)(a_base + mt * 16 * 256 + ks);
#pragma unroll
            for (int nt = 0; nt < 4; nt++)
                bf[nt] = *(const bh8*)(X + (nt * 16 + lr) * MP + ks + lq * 8);
#pragma unroll
            for (int mt = 0; mt < 4; mt++)
#pragma unroll
                for (int nt = 0; nt < 4; nt++)
                    acc[mt][nt] = __builtin_amdgcn_mfma_f32_16x16x32_bf16(af[mt], bf[nt],
                                                                          acc[mt][nt], 0, 0, 0);
        }
#pragma unroll
        for (int mt = 0; mt < 4; mt++) {
            int h0 = wv * 64 + mt * 16 + lq * 4;
            float4 bb = *(const float4*)(b1 + h0);
#pragma unroll
            for (int nt = 0; nt < 4; nt++) {
                hv[mt][nt][0] = f2bf(swish_f(acc[mt][nt][0] + bb.x));
                hv[mt][nt][1] = f2bf(swish_f(acc[mt][nt][1] + bb.y));
                hv[mt][nt][2] = f2bf(swish_f(acc[mt][nt][2] + bb.z));
                hv[mt][nt][3] = f2bf(swish_f(acc[mt][nt][3] + bb.w));
            }
        }
    }
    __syncthreads();   // done reading A -> buffer becomes H

#pragma unroll
    for (int mt = 0; mt < 4; mt++) {
        int h0 = wv * 64 + mt * 16 + lq * 4;
#pragma unroll
        for (int nt = 0; nt < 4; nt++) {
            int e = nt * 16 + lr;
            *(bh4*)(X + e * MP + h0) = hv[mt][nt];
        }
    }
    __syncthreads();

    {
        f32x4 acc[2][4];
#pragma unroll
        for (int a = 0; a < 2; a++)
#pragma unroll
            for (int b = 0; b < 4; b++) acc[a][b] = (f32x4)(0.f);

        const short* a_base = W2T + (size_t)(wv * 32 + lr) * 256 + lq * 8;
        for (int ks = 0; ks < 256; ks += 32) {
            bh8 af[2], bf[4];
#pragma unroll
            for (int mt = 0; mt < 2; mt++) af[mt] = *(const bh8*)(a_base + mt * 16 * 256 + ks);
#pragma unroll
            for (int nt = 0; nt < 4; nt++)
                bf[nt] = *(const bh8*)(X + (nt * 16 + lr) * MP + ks + lq * 8);
#pragma unroll
            for (int mt = 0; mt < 2; mt++)
#pragma unroll
                for (int nt = 0; nt < 4; nt++)
                    acc[mt][nt] = __builtin_amdgcn_mfma_f32_16x16x32_bf16(af[mt], bf[nt],
                                                                          acc[mt][nt], 0, 0, 0);
        }
#pragma unroll
        for (int mt = 0; mt < 2; mt++) {
            int c0 = wv * 32 + mt * 16 + lq * 4;
            float4 bb = *(const float4*)(b2 + c0);
#pragma unroll
            for (int nt = 0; nt < 4; nt++) {
                int nl = nt * 16 + lr;
                int gn = n0 + nl;
                if (gn < N_NODES) {
                    float4 xv = *(const float4*)(x + (size_t)gn * 128 + c0);
                    float4 nv;
                    nv.x = xv.x + acc[mt][nt][0] + bb.x;
                    nv.y = xv.y + acc[mt][nt][1] + bb.y;
                    nv.z = xv.z + acc[mt][nt][2] + bb.z;
                    nv.w = xv.w + acc[mt][nt][3] + bb.w;
                    *(float4*)(x + (size_t)gn * 128 + c0) = nv;
                    bh4 pk;
                    pk[0] = f2bf(nv.x); pk[1] = f2bf(nv.y); pk[2] = f2bf(nv.z); pk[3] = f2bf(nv.w);
                    *(bh4*)(xb + (size_t)gn * 128 + c0) = pk;
                }
            }
        }
    }
}

// ---------------- Output head: MFMA GEMM + in-register h-reduction ----------------
__global__ __launch_bounds__(256, 4) void out_head_mfma(
    const short* __restrict__ xb, const short* __restrict__ oW1T,
    const float* __restrict__ b1, const float* __restrict__ w2,
    const float* __restrict__ b2, float* __restrict__ sval) {
    __shared__ __align__(16) short Xs[64 * YP];
    __shared__ float red2[4][64];
    const int tid = threadIdx.x;
    const int n0 = blockIdx.x * 64;
    const int wv = tid >> 6;
    const int ln = tid & 63;
    const int lr = ln & 15;
    const int lq = ln >> 4;

    {
        int row = tid >> 2, p = tid & 3;
        int gn = n0 + row;
        if (gn < N_NODES) {
            const int4* xp = (const int4*)(xb + (size_t)gn * 128) + p * 4;
#pragma unroll
            for (int i = 0; i < 4; i++) *(int4*)(Xs + row * YP + (p * 4 + i) * 8) = xp[i];
        } else {
            int4 z4 = make_int4(0, 0, 0, 0);
#pragma unroll
            for (int i = 0; i < 4; i++) *(int4*)(Xs + row * YP + (p * 4 + i) * 8) = z4;
        }
    }
    __syncthreads();

    f32x4 acc[4][4];
#pragma unroll
    for (int a = 0; a < 4; a++)
#pragma unroll
        for (int b = 0; b < 4; b++) acc[a][b] = (f32x4)(0.f);

    const short* a_base = oW1T + (size_t)(wv * 64 + lr) * 128 + lq * 8;
#pragma unroll
    for (int ks = 0; ks < 128; ks += 32) {
        bh8 af[4], bf[4];
#pragma unroll
        for (int mt = 0; mt < 4; mt++) af[mt] = *(const bh8*)(a_base + mt * 16 * 128 + ks);
#pragma unroll
        for (int nt = 0; nt < 4; nt++)
            bf[nt] = *(const bh8*)(Xs + (nt * 16 + lr) * YP + ks + lq * 8);
#pragma unroll
        for (int mt = 0; mt < 4; mt++)
#pragma unroll
            for (int nt = 0; nt < 4; nt++)
                acc[mt][nt] = __builtin_amdgcn_mfma_f32_16x16x32_bf16(af[mt], bf[nt],
                                                                      acc[mt][nt], 0, 0, 0);
    }

    // per-thread partial over its 16 h values, for its 4 nodes
    float part[4] = {0.f, 0.f, 0.f, 0.f};
#pragma unroll
    for (int mt = 0; mt < 4; mt++) {
        int h0 = wv * 64 + mt * 16 + lq * 4;
        float4 bb = *(const float4*)(b1 + h0);
        float4 ww = *(const float4*)(w2 + h0);
#pragma unroll
        for (int nt = 0; nt < 4; nt++) {
            part[nt] += swish_f(acc[mt][nt][0] + bb.x) * ww.x
                      + swish_f(acc[mt][nt][1] + bb.y) * ww.y
                      + swish_f(acc[mt][nt][2] + bb.z) * ww.z
                      + swish_f(acc[mt][nt][3] + bb.w) * ww.w;
        }
    }
    // butterfly over lq (lanes lr, lr+16, lr+32, lr+48), then cross-wave via LDS
#pragma unroll
    for (int nt = 0; nt < 4; nt++) {
        float v = part[nt];
        v += __shfl_xor(v, 16, 64);
        v += __shfl_xor(v, 32, 64);
        if (lq == 0) red2[wv][nt * 16 + lr] = v;
    }
    __syncthreads();
    if (tid < 64) {
        int gn = n0 + tid;
        if (gn < N_NODES)
            sval[gn] = red2[0][tid] + red2[1][tid] + red2[2][tid] + red2[3][tid] + b2[0];
    }
}

__global__ void out_stage2(const float* __restrict__ sval, const int* __restrict__ batch,
                           float* __restrict__ partial) {
    __shared__ float part[N_GRAPHS];
    const int tid = threadIdx.x;
    if (tid < N_GRAPHS) part[tid] = 0.f;
    __syncthreads();
    const int per_block = (N_NODES + OB2 - 1) / OB2;
    const int start = blockIdx.x * per_block;
    const int end = min(start + per_block, N_NODES);
    const int per_thread = (per_block + 255) / 256;
    int s = start + tid * per_thread;
    int e = min(s + per_thread, end);
    if (s < e) {
        int g = batch[s];
        float a = sval[s];
        for (int n = s + 1; n < e; n++) {
            int gg = batch[n];
            float v = sval[n];
            if (gg != g) {
                atomicAdd(&part[g], a);
                a = v;
                g = gg;
            } else {
                a += v;
            }
        }
        atomicAdd(&part[g], a);
    }
    __syncthreads();
    if (tid < N_GRAPHS) partial[blockIdx.x * N_GRAPHS + tid] = part[tid];
}

__global__ void out_stage3(const float* __restrict__ partial, float* __restrict__ out) {
    int g = threadIdx.x;
    if (g >= N_GRAPHS) return;
    float s = 0.f;
    for (int b = 0; b < OB2; b++) s += partial[b * N_GRAPHS + g];
    out[g] = s;
}

extern "C" void kernel_launch(void* const* d_in, const int* in_sizes, int n_in,
                              void* d_out, int out_size, void* d_ws, size_t ws_size,
                              hipStream_t stream) {
    const float* positions = (const float*)d_in[0];
    const float* edge_shift = (const float*)d_in[1];
    const float* lattice = (const float*)d_in[2];
    const int* atomic_numbers = (const int*)d_in[3];
    const int* edge_index = (const int*)d_in[4];
    const int* batch = (const int*)d_in[5];
    const float* embed_w = (const float*)d_in[6];
    const float* edge_w1 = (const float*)d_in[7];
    const float* edge_b1 = (const float*)d_in[8];
    const float* edge_w2 = (const float*)d_in[9];
    const float* edge_b2 = (const float*)d_in[10];
    const float* node_w1 = (const float*)d_in[11];
    const float* node_b1 = (const float*)d_in[12];
    const float* node_w2 = (const float*)d_in[13];
    const float* node_b2 = (const float*)d_in[14];
    const float* out_w1 = (const float*)d_in[15];
    const float* out_b1 = (const float*)d_in[16];
    const float* out_w2 = (const float*)d_in[17];
    const float* out_b2 = (const float*)d_in[18];

    // workspace layout (every piece 16B-aligned; ~110 MB total)
    float* ws = (float*)d_ws;
    float* x = ws;                                   // N*128 f32
    short* xb = (short*)(x + (size_t)N_NODES * 128); // N*128 bf16
    short* aggb = xb + (size_t)N_NODES * 128;        // N*128 bf16
    short* ydb = aggb + (size_t)N_NODES * 128;       // N*256 bf16
    short* ysb = ydb + (size_t)N_NODES * 256;        // N*256 bf16
    short* WcT = ysb + (size_t)N_NODES * 256;        // 3*512*128 bf16
    short* eW2T = WcT + 3 * 512 * 128;               // 3*128*256
    short* nW1T = eW2T + 3 * 128 * 256;              // 3*256*256
    short* nW2T = nW1T + 3 * 256 * 256;              // 3*128*256
    short* oW1T = nW2T + 3 * 128 * 256;              // 256*128
    int* deg = (int*)(oW1T + 256 * 128);             // N
    int* fillc = deg + N_NODES;                      // N
    int* sc = fillc + N_NODES;                       // N
    int* bsum = sc + N_NODES;                        // 128
    int4* epack = (int4*)(bsum + 128);               // E * 16B (dst-sorted src,dst,d2)
    int* rowptr = (int*)(epack + N_EDGES);           // N+1
    float* sval = (float*)(rowptr + N_NODES + 4);    // N
    float* partial = sval + N_NODES;                 // OB2*N_GRAPHS

    (void)hipMemsetAsync(deg, 0, N_NODES * sizeof(int), stream);
    (void)hipMemsetAsync(fillc, 0, N_NODES * sizeof(int), stream);

    // weight transpose+cvt (tiny)
    {
        int tc = 3 * 512 * 128;
        cvt_wc_kernel<<<(tc + 255) / 256, 256, 0, stream>>>(edge_w1, WcT, tc);
        int t2 = 3 * 128 * 256;
        cvt_wT_kernel<<<(t2 + 255) / 256, 256, 0, stream>>>(edge_w2, eW2T, 256, 128, 256, t2);
        int t3 = 3 * 256 * 256;
        cvt_wT_kernel<<<(t3 + 255) / 256, 256, 0, stream>>>(node_w1, nW1T, 256, 256, 256, t3);
        cvt_wT_kernel<<<(t2 + 255) / 256, 256, 0, stream>>>(node_w2, nW2T, 256, 128, 256, t2);
        int t4 = 256 * 128;
        cvt_wT_kernel<<<(t4 + 255) / 256, 256, 0, stream>>>(out_w1, oW1T, 128, 256, 128, t4);
    }

    embed_kernel<<<(N_NODES * 128) / 256, 256, 0, stream>>>(embed_w, atomic_numbers, x, xb);

    // CSR counting sort by dst (d2 computed inline in fill)
    {
        int nscan = (N_NODES + SCAN_BS - 1) / SCAN_BS;
        hist_kernel<<<(N_EDGES + 255) / 256, 256, 0, stream>>>(edge_index, deg);
        scan1_kernel<<<nscan, SCAN_BS, 0, stream>>>(deg, sc, bsum, N_NODES);
        scan2_kernel<<<1, 128, 0, stream>>>(bsum, nscan);
        scan3_kernel<<<(N_NODES + SCAN_BS) / SCAN_BS + 1, SCAN_BS, 0, stream>>>(
            sc, deg, bsum, rowptr, N_NODES, N_EDGES);
        fill_kernel<<<(N_EDGES + 255) / 256, 256, 0, stream>>>(
            positions, edge_shift, lattice, edge_index, batch, rowptr, fillc, epack);
    }

    const int nblk = (N_NODES + 63) / 64;
    for (int l = 0; l < N_LAYERS; l++) {
        y_precompute<<<nblk * 2, 256, 0, stream>>>(
            xb, WcT + (size_t)l * 512 * 128, edge_b1 + (size_t)l * 256, ydb, ysb);
        edge_mlp_csr<<<N_NODES / DQ, 256, 0, stream>>>(
            ydb, ysb, edge_w1 + ((size_t)l * 257 + 256) * 256, epack, rowptr,
            eW2T + (size_t)l * 128 * 256, edge_b2 + (size_t)l * 128, aggb);
        node_mlp_mfma<<<nblk, 256, 0, stream>>>(
            x, xb, aggb,
            nW1T + (size_t)l * 256 * 256, node_b1 + (size_t)l * 256,
            nW2T + (size_t)l * 128 * 256, node_b2 + (size_t)l * 128);
    }
    out_head_mfma<<<nblk, 256, 0, stream>>>(xb, oW1T, out_b1, out_w2, out_b2, sval);
    out_stage2<<<OB2, 256, 0, stream>>>(sval, batch, partial);
    out_stage3<<<1, 64, 0, stream>>>(partial, (float*)d_out);
}

// Round 15
// 882.960 us; speedup vs baseline: 1.0423x; 1.0423x over previous
//
#include <hip/hip_runtime.h>
#include <hip/hip_bf16.h>

#define N_NODES 50000
#define N_EDGES 800000
#define N_GRAPHS 32
#define NODE_DIM 128
#define HIDDEN 256
#define N_LAYERS 3

typedef __attribute__((ext_vector_type(8))) short bh8;   // 8 bf16 (4 VGPRs)
typedef __attribute__((ext_vector_type(4))) short bh4;   // 4 bf16 (8B)
typedef __attribute__((ext_vector_type(4))) float f32x4; // MFMA acc

#define MP 264  // M/H tile pitch (bf16)
#define YP 136  // X-tile pitch (bf16)
#define DQ 16   // dst nodes per edge-CSR block
#define YDP 264 // ydc LDS pitch (shorts)
#define WSP 36  // wsh pitch (floats)
#define SWP 40  // per-wave S-tile pitch (shorts): 80B rows -> 2-way-free b128 reads
#define STP 136 // epilogue agg staging pitch (shorts)
#define SCAN_BS 512
#define OB2 32  // out_stage2 blocks

// swish via hw rcp (avoids full-precision fp32 divide sequence)
__device__ __forceinline__ float swish_f(float v) {
    return v * __builtin_amdgcn_rcpf(1.0f + __expf(-v));
}

// round-half-up bf16 (2 int ops; differs from RNE only on exact ties)
__device__ __forceinline__ short f2bf(float f) {
    union { float f; unsigned u; } v;
    v.f = f;
    return (short)((v.u + 0x8000u) >> 16);
}

__device__ __forceinline__ float bf2f(short s) {
    union { unsigned u; float f; } v;
    v.u = ((unsigned)(unsigned short)s) << 16;
    return v.f;
}

// x[n][c] = embed[z[n]][c]; also bf16 mirror
__global__ void embed_kernel(const float* __restrict__ emb, const int* __restrict__ z,
                             float* __restrict__ x, short* __restrict__ xb) {
    int i = blockIdx.x * blockDim.x + threadIdx.x;
    int n = i >> 7, c = i & 127;
    float v = emb[z[n] * 128 + c];
    x[i] = v;
    xb[i] = f2bf(v);
}

// out[l][h][k] = bf16(in[l][k][h]) for k<K_in else 0
__global__ void cvt_wT_kernel(const float* __restrict__ in, short* __restrict__ out,
                              int K_in, int H, int K_pad, int total) {
    int i = blockIdx.x * blockDim.x + threadIdx.x;
    if (i >= total) return;
    int k = i % K_pad;
    int t = i / K_pad;
    int h = t % H;
    int l = t / H;
    out[i] = (k < K_in) ? f2bf(in[((size_t)l * K_in + k) * H + h]) : (short)0;
}

// combined edge-W1 transpose: out[l][m][k] bf16, m<256 -> W1[l][k][m] (dst part),
// m>=256 -> W1[l][128+k][m-256] (src part). K=128 exact.
__global__ void cvt_wc_kernel(const float* __restrict__ in, short* __restrict__ out, int total) {
    int i = blockIdx.x * blockDim.x + threadIdx.x;
    if (i >= total) return;
    int k = i & 127;
    int t = i >> 7;
    int m = t & 511;
    int l = t >> 9;
    size_t src;
    if (m < 256) src = ((size_t)l * 257 + k) * 256 + m;
    else src = ((size_t)l * 257 + 128 + k) * 256 + (m - 256);
    out[i] = f2bf(in[src]);
}

// ---- CSR counting-sort build ----
__global__ void hist_kernel(const int* __restrict__ eidx, int* __restrict__ deg) {
    int e = blockIdx.x * blockDim.x + threadIdx.x;
    if (e >= N_EDGES) return;
    atomicAdd(&deg[eidx[N_EDGES + e]], 1);
}

__global__ void scan1_kernel(const int* __restrict__ deg, int* __restrict__ sc,
                             int* __restrict__ bsum, int n) {
    __shared__ int s[SCAN_BS];
    int i = blockIdx.x * SCAN_BS + threadIdx.x;
    int v = (i < n) ? deg[i] : 0;
    s[threadIdx.x] = v;
    __syncthreads();
    for (int off = 1; off < SCAN_BS; off <<= 1) {
        int t = (threadIdx.x >= off) ? s[threadIdx.x - off] : 0;
        __syncthreads();
        s[threadIdx.x] += t;
        __syncthreads();
    }
    if (i < n) sc[i] = s[threadIdx.x];
    if (threadIdx.x == SCAN_BS - 1) bsum[blockIdx.x] = s[SCAN_BS - 1];
}

__global__ void scan2_kernel(int* __restrict__ bsum, int nb) {  // 1 block, 128 threads
    __shared__ int s[128];
    int v = (threadIdx.x < nb) ? bsum[threadIdx.x] : 0;
    s[threadIdx.x] = v;
    __syncthreads();
    for (int off = 1; off < 128; off <<= 1) {
        int t = (threadIdx.x >= off) ? s[threadIdx.x - off] : 0;
        __syncthreads();
        s[threadIdx.x] += t;
        __syncthreads();
    }
    if (threadIdx.x < nb) bsum[threadIdx.x] = s[threadIdx.x];
}

__global__ void scan3_kernel(const int* __restrict__ sc, const int* __restrict__ deg,
                             const int* __restrict__ bsum, int* __restrict__ rowptr,
                             int n, int total) {
    int i = blockIdx.x * SCAN_BS + threadIdx.x;
    if (i > n) return;
    if (i == n) { rowptr[n] = total; return; }
    int off = (blockIdx.x > 0) ? bsum[blockIdx.x - 1] : 0;
    rowptr[i] = sc[i] - deg[i] + off;
}

// scatter into dst-sorted order, packing (src, dst, d2); d2 computed inline
__global__ void fill_kernel(const float* __restrict__ pos, const float* __restrict__ shift,
                            const float* __restrict__ lattice, const int* __restrict__ eidx,
                            const int* __restrict__ batch, const int* __restrict__ rowptr,
                            int* __restrict__ fillc, int4* __restrict__ epack) {
    int e = blockIdx.x * blockDim.x + threadIdx.x;
    if (e >= N_EDGES) return;
    int s = eidx[e];
    int d = eidx[N_EDGES + e];
    int b = batch[s];
    const float* lat = lattice + b * 9;
    float s0 = shift[e * 3 + 0], s1 = shift[e * 3 + 1], s2 = shift[e * 3 + 2];
    float acc = 0.f;
#pragma unroll
    for (int j = 0; j < 3; j++) {
        float v = pos[d * 3 + j] - pos[s * 3 + j] + s0 * lat[j] + s1 * lat[3 + j] + s2 * lat[6 + j];
        acc += v * v;
    }
    int p = rowptr[d] + atomicAdd(&fillc[d], 1);
    epack[p] = make_int4(s, d, __float_as_int(acc), 0);
}

// ---------------- per-layer node-level GEMM1 precompute ----------------
__global__ __launch_bounds__(256, 4) void y_precompute(
    const short* __restrict__ xb, const short* __restrict__ WcT,
    const float* __restrict__ b1, short* __restrict__ ydb, short* __restrict__ ysb) {
    __shared__ __align__(16) short B[64 * MP];  // X [64][YP] then Y [64][MP]
    const int tid = threadIdx.x;
    const int half = blockIdx.x & 1;
    const int n0 = (blockIdx.x >> 1) * 64;
    const int wv = tid >> 6;
    const int ln = tid & 63;
    const int lr = ln & 15;
    const int lq = ln >> 4;

    {
        int row = tid >> 2, p = tid & 3;
        int gn = n0 + row;
        if (gn < N_NODES) {
            const int4* xp = (const int4*)(xb + (size_t)gn * 128) + p * 4;
#pragma unroll
            for (int i = 0; i < 4; i++) *(int4*)(B + row * YP + (p * 4 + i) * 8) = xp[i];
        } else {
            int4 z4 = make_int4(0, 0, 0, 0);
#pragma unroll
            for (int i = 0; i < 4; i++) *(int4*)(B + row * YP + (p * 4 + i) * 8) = z4;
        }
    }
    __syncthreads();

    f32x4 acc[4][4];
#pragma unroll
    for (int a = 0; a < 4; a++)
#pragma unroll
        for (int b = 0; b < 4; b++) acc[a][b] = (f32x4)(0.f);

    const short* a_base = WcT + (size_t)(half * 256 + wv * 64 + lr) * 128 + lq * 8;
#pragma unroll
    for (int ks = 0; ks < 128; ks += 32) {
        bh8 af[4], bf[4];
#pragma unroll
        for (int mt = 0; mt < 4; mt++) af[mt] = *(const bh8*)(a_base + mt * 16 * 128 + ks);
#pragma unroll
        for (int nt = 0; nt < 4; nt++)
            bf[nt] = *(const bh8*)(B + (nt * 16 + lr) * YP + ks + lq * 8);
#pragma unroll
        for (int mt = 0; mt < 4; mt++)
#pragma unroll
            for (int nt = 0; nt < 4; nt++)
                acc[mt][nt] = __builtin_amdgcn_mfma_f32_16x16x32_bf16(af[mt], bf[nt],
                                                                      acc[mt][nt], 0, 0, 0);
    }
    __syncthreads();   // done reading X -> B becomes Y [64][MP]

#pragma unroll
    for (int mt = 0; mt < 4; mt++) {
        int h0 = wv * 64 + mt * 16 + lq * 4;
        float4 bb = half ? make_float4(0.f, 0.f, 0.f, 0.f) : *(const float4*)(b1 + h0);
#pragma unroll
        for (int nt = 0; nt < 4; nt++) {
            bh4 pk;
            pk[0] = f2bf(acc[mt][nt][0] + bb.x);
            pk[1] = f2bf(acc[mt][nt][1] + bb.y);
            pk[2] = f2bf(acc[mt][nt][2] + bb.z);
            pk[3] = f2bf(acc[mt][nt][3] + bb.w);
            *(bh4*)(B + (nt * 16 + lr) * MP + h0) = pk;
        }
    }
    __syncthreads();

    // coalesced copy: instr i writes 64 consecutive int4 (1KB contiguous)
    short* outp = half ? ysb : ydb;
    int4* og = (int4*)(outp + (size_t)n0 * 256);
#pragma unroll
    for (int i = 0; i < 8; i++) {
        int f = i * 256 + tid;             // flat int4 index over [64][256]
        int row = f >> 5;
        if (n0 + row < N_NODES)
            og[f] = *(const int4*)(B + row * MP + (f & 31) * 8);
    }
}

// ---------------- Edge MLP, CSR dst-centric, MFMA segment aggregation ----------------
// r12 form (best verified: 177.5us, VGPR 84, zero spill). r13's bank swizzle cut
// conflicts 32% but regressed time (conflicts were overlap-hidden; swizzle
// perturbed the hot-loop schedule) -> reverted. (256,3) releases the 64-VGPR
// clamp; usage 65..128 VGPRs keeps 4 waves/SIMD (m69 steps) so no occupancy loss.
__global__ __launch_bounds__(256, 3) void edge_mlp_csr(
    const short* __restrict__ ydb, const short* __restrict__ ysb,
    const float* __restrict__ w1c,   // [256] f32: W1 row 256 (the d2 row)
    const int4* __restrict__ epack,  // dst-sorted (src, dst, d2)
    const int* __restrict__ rowptr,
    const short* __restrict__ W2T,   // [128][256] bf16
    const float* __restrict__ b2,
    short* __restrict__ aggb) {
    __shared__ __align__(16) short MB[32 * MP];     // 16896B: M tile
    __shared__ __align__(16) short Stw[4 * 32 * SWP]; // 10240B: per-wave S tiles / agg staging
    __shared__ __align__(16) short ydc[DQ * YDP];   // 8448B
    __shared__ __align__(16) float wsh[8 * WSP];    // 1152B
    __shared__ int s_dl[32];
    const int tid = threadIdx.x;
    const int n0 = blockIdx.x * DQ;
    const int wv = tid >> 6;
    const int ln = tid & 63;
    const int lr = ln & 15;
    const int lq = ln >> 4;
    const int el = tid >> 3;
    const int p = tid & 7;

    const int estart = rowptr[n0];
    const int eend = rowptr[n0 + DQ];

    // ---- phase 0: stage yd rows (coalesced), w1c -> wsh ----
    {
        const int4* src = (const int4*)(ydb + (size_t)n0 * 256);  // 512 int4 contiguous
        int4* dst = (int4*)ydc;
#pragma unroll
        for (int i = 0; i < 2; i++) {
            int f = tid + i * 256;
            dst[(f >> 5) * 33 + (f & 31)] = src[f];   // YDP=264 shorts = 33 int4
        }
        wsh[(tid >> 5) * WSP + (tid & 31)] = w1c[tid];
    }
    __syncthreads();

    f32x4 acc2[2];
    acc2[0] = (f32x4)(0.f);
    acc2[1] = (f32x4)(0.f);
    short* Sw = Stw + wv * 32 * SWP;   // wave-private [32 ch][SWP] bf16

    const int nch = (eend - estart + 31) >> 5;
    for (int ch = 0; ch < nch; ch++) {
        const int e0 = estart + ch * 32;

        // ---- stage A: gather ys[src] + ydc[dl] + d2*wsh -> swish -> M (8 thr/edge) ----
        {
            int e = e0 + el;
            bool valid = e < eend;
            int s = 0, dl = -1;
            float d2v = 0.f;
            if (valid) {
                int4 ep = epack[e];
                s = ep.x;
                dl = ep.y - n0;
                d2v = __int_as_float(ep.z);
            }
            if (p == 0) s_dl[el] = dl;
            if (valid) {
                const int4* ys = (const int4*)(ysb + (size_t)s * 256) + p * 4;
                const short* yl = ydc + dl * YDP + p * 32;
                const float* wl = wsh + p * WSP;
#pragma unroll
                for (int h = 0; h < 2; h++) {
                    int4 bv0 = ys[h * 2];
                    int4 bv1 = ys[h * 2 + 1];
#pragma unroll
                    for (int qq = 0; qq < 2; qq++) {
                        int q = h * 2 + qq;
                        union { int4 v; short s2[8]; } b, m;
                        b.v = qq ? bv1 : bv0;
                        bh8 av = *(const bh8*)(yl + q * 8);
                        float4 w0 = *(const float4*)(wl + q * 8);
                        float4 w1 = *(const float4*)(wl + q * 8 + 4);
                        m.s2[0] = f2bf(swish_f(bf2f(av[0]) + bf2f(b.s2[0]) + d2v * w0.x));
                        m.s2[1] = f2bf(swish_f(bf2f(av[1]) + bf2f(b.s2[1]) + d2v * w0.y));
                        m.s2[2] = f2bf(swish_f(bf2f(av[2]) + bf2f(b.s2[2]) + d2v * w0.z));
                        m.s2[3] = f2bf(swish_f(bf2f(av[3]) + bf2f(b.s2[3]) + d2v * w0.w));
                        m.s2[4] = f2bf(swish_f(bf2f(av[4]) + bf2f(b.s2[4]) + d2v * w1.x));
                        m.s2[5] = f2bf(swish_f(bf2f(av[5]) + bf2f(b.s2[5]) + d2v * w1.y));
                        m.s2[6] = f2bf(swish_f(bf2f(av[6]) + bf2f(b.s2[6]) + d2v * w1.z));
                        m.s2[7] = f2bf(swish_f(bf2f(av[7]) + bf2f(b.s2[7]) + d2v * w1.w));
                        *(int4*)(MB + el * MP + p * 32 + q * 8) = m.v;
                    }
                }
            } else {
                int4 z4 = make_int4(0, 0, 0, 0);
#pragma unroll
                for (int q = 0; q < 4; q++) *(int4*)(MB + el * MP + p * 32 + q * 8) = z4;
            }
        }
        __syncthreads();   // (A) M + s_dl ready

        // ---- GEMM2: 128 ch x 32 edges, each wave 32 ch; S -> wave-private bf16 tile ----
        {
            f32x4 acc[2][2];
#pragma unroll
            for (int a = 0; a < 2; a++)
#pragma unroll
                for (int b = 0; b < 2; b++) acc[a][b] = (f32x4)(0.f);

            const short* a_base = W2T + (size_t)(wv * 32 + lr) * 256 + lq * 8;
            for (int ks = 0; ks < 256; ks += 32) {
                bh8 af[2], bf[2];
#pragma unroll
                for (int mt = 0; mt < 2; mt++) af[mt] = *(const bh8*)(a_base + mt * 16 * 256 + ks);
#pragma unroll
                for (int nt = 0; nt < 2; nt++)
                    bf[nt] = *(const bh8*)(MB + (nt * 16 + lr) * MP + ks + lq * 8);
#pragma unroll
                for (int mt = 0; mt < 2; mt++)
#pragma unroll
                    for (int nt = 0; nt < 2; nt++)
                        acc[mt][nt] = __builtin_amdgcn_mfma_f32_16x16x32_bf16(af[mt], bf[nt],
                                                                              acc[mt][nt], 0, 0, 0);
            }
            // swish2 + bf16 -> Sw[row=ch (32), col=e (32)]  (wave-private, no barrier)
#pragma unroll
            for (int mt = 0; mt < 2; mt++) {
                int r0 = mt * 16 + lq * 4;
                float4 bb = *(const float4*)(b2 + wv * 32 + r0);
#pragma unroll
                for (int nt = 0; nt < 2; nt++) {
                    int e = nt * 16 + lr;
                    Sw[(r0 + 0) * SWP + e] = f2bf(swish_f(acc[mt][nt][0] + bb.x));
                    Sw[(r0 + 1) * SWP + e] = f2bf(swish_f(acc[mt][nt][1] + bb.y));
                    Sw[(r0 + 2) * SWP + e] = f2bf(swish_f(acc[mt][nt][2] + bb.z));
                    Sw[(r0 + 3) * SWP + e] = f2bf(swish_f(acc[mt][nt][3] + bb.w));
                }
            }
        }

        // ---- seg-MFMA aggregation: acc2[mt] += Seg @ S  ----
        {
            bh8 af;
#pragma unroll
            for (int j = 0; j < 8; j++)
                af[j] = (s_dl[lq * 8 + j] == lr) ? (short)0x3F80 : (short)0;
#pragma unroll
            for (int mt = 0; mt < 2; mt++) {
                bh8 bfv = *(const bh8*)(Sw + (mt * 16 + lr) * SWP + lq * 8);
                acc2[mt] = __builtin_amdgcn_mfma_f32_16x16x32_bf16(af, bfv, acc2[mt], 0, 0, 0);
            }
        }
        __syncthreads();   // (B) M-reads + s_dl-reads done before next stageA
    }

    // ---- epilogue: acc2 (C layout: row dl=(lq*4+j), col ch=lr) -> LDS -> coalesced bf16 ----
#pragma unroll
    for (int mt = 0; mt < 2; mt++)
#pragma unroll
        for (int j = 0; j < 4; j++)
            Stw[(lq * 4 + j) * STP + wv * 32 + mt * 16 + lr] = f2bf(acc2[mt][j]);
    __syncthreads();
    {
        int row = tid >> 4, c16 = tid & 15;
        *(int4*)(aggb + ((size_t)(n0 + row)) * 128 + c16 * 8) =
            *(const int4*)(Stw + row * STP + c16 * 8);
    }
}

// ---------------- Node MLP (MFMA, single LDS buffer, 4 blocks/CU) ----------------
__global__ __launch_bounds__(256, 4) void node_mlp_mfma(
    float* __restrict__ x, short* __restrict__ xb, const short* __restrict__ aggb,
    const short* __restrict__ W1T, const float* __restrict__ b1,
    const short* __restrict__ W2T, const float* __restrict__ b2) {
    __shared__ __align__(16) short X[64 * MP];
    const int tid = threadIdx.x;
    const int n0 = blockIdx.x * 64;
    const int wv = tid >> 6;
    const int ln = tid & 63;
    const int lr = ln & 15;
    const int lq = ln >> 4;

    {
        int row = tid >> 2, p = tid & 3;
        int gn = n0 + row;
        if (gn < N_NODES) {
            const int4* xp = (const int4*)(xb + (size_t)gn * 128);
            const int4* ap = (const int4*)(aggb + (size_t)gn * 128);
#pragma unroll
            for (int q = 0; q < 4; q++) {
                int c = p * 4 + q;
                *(int4*)(X + row * MP + c * 8) = xp[c];
                *(int4*)(X + row * MP + 128 + c * 8) = ap[c];
            }
        } else {
            int4 z4 = make_int4(0, 0, 0, 0);
#pragma unroll
            for (int q = 0; q < 8; q++) *(int4*)(X + row * MP + (p * 8 + q) * 8) = z4;
        }
    }
    __syncthreads();

    bh4 hv[4][4];
    {
        f32x4 acc[4][4];
#pragma unroll
        for (int a = 0; a < 4; a++)
#pragma unroll
            for (int b = 0; b < 4; b++) acc[a][b] = (f32x4)(0.f);

        const short* a_base = W1T + (size_t)(wv * 64 + lr) * 256 + lq * 8;
        for (int ks = 0; ks < 256; ks += 32) {
            bh8 af[4], bf[4];
#pragma unroll
            for (int mt = 0; mt < 4; mt++) af[mt] = *(const bh8*)(a_base + mt * 16 * 256 + ks);
#pragma unroll
            for (int nt = 0; nt < 4; nt++)
                bf[nt] = *(const bh8*)(X + (nt * 16 + lr) * MP + ks + lq * 8);
#pragma unroll
            for (int mt = 0; mt < 4; mt++)
#pragma unroll
                for (int nt = 0; nt < 4; nt++)
                    acc[mt][nt] = __builtin_amdgcn_mfma_f32_16x16x32_bf16(af[mt], bf[nt],
                                                                          acc[mt][nt], 0, 0, 0);
        }
#pragma unroll
        for (int mt = 0; mt < 4; mt++) {
            int h0 = wv * 64 + mt * 16 + lq * 4;
            float4 bb = *(const float4*)(b1 + h0);
#pragma unroll
            for (int nt = 0; nt < 4; nt++) {
                hv[mt][nt][0] = f2bf(swish_f(acc[mt][nt][0] + bb.x));
                hv[mt][nt][1] = f2bf(swish_f(acc[mt][nt][1] + bb.y));
                hv[mt][nt][2] = f2bf(swish_f(acc[mt][nt][2] + bb.z));
                hv[mt][nt][3] = f2bf(swish_f(acc[mt][nt][3] + bb.w));
            }
        }
    }
    __syncthreads();   // done reading A -> buffer becomes H

#pragma unroll
    for (int mt = 0; mt < 4; mt++) {
        int h0 = wv * 64 + mt * 16 + lq * 4;
#pragma unroll
        for (int nt = 0; nt < 4; nt++) {
            int e = nt * 16 + lr;
            *(bh4*)(X + e * MP + h0) = hv[mt][nt];
        }
    }
    __syncthreads();

    {
        f32x4 acc[2][4];
#pragma unroll
        for (int a = 0; a < 2; a++)
#pragma unroll
            for (int b = 0; b < 4; b++) acc[a][b] = (f32x4)(0.f);

        const short* a_base = W2T + (size_t)(wv * 32 + lr) * 256 + lq * 8;
        for (int ks = 0; ks < 256; ks += 32) {
            bh8 af[2], bf[4];
#pragma unroll
            for (int mt = 0; mt < 2; mt++) af[mt] = *(const bh8*)(a_base + mt * 16 * 256 + ks);
#pragma unroll
            for (int nt = 0; nt < 4; nt++)
                bf[nt] = *(const bh8*)(X + (nt * 16 + lr) * MP + ks + lq * 8);
#pragma unroll
            for (int mt = 0; mt < 2; mt++)
#pragma unroll
                for (int nt = 0; nt < 4; nt++)
                    acc[mt][nt] = __builtin_amdgcn_mfma_f32_16x16x32_bf16(af[mt], bf[nt],
                                                                          acc[mt][nt], 0, 0, 0);
        }
#pragma unroll
        for (int mt = 0; mt < 2; mt++) {
            int c0 = wv * 32 + mt * 16 + lq * 4;
            float4 bb = *(const float4*)(b2 + c0);
#pragma unroll
            for (int nt = 0; nt < 4; nt++) {
                int nl = nt * 16 + lr;
                int gn = n0 + nl;
                if (gn < N_NODES) {
                    float4 xv = *(const float4*)(x + (size_t)gn * 128 + c0);
                    float4 nv;
                    nv.x = xv.x + acc[mt][nt][0] + bb.x;
                    nv.y = xv.y + acc[mt][nt][1] + bb.y;
                    nv.z = xv.z + acc[mt][nt][2] + bb.z;
                    nv.w = xv.w + acc[mt][nt][3] + bb.w;
                    *(float4*)(x + (size_t)gn * 128 + c0) = nv;
                    bh4 pk;
                    pk[0] = f2bf(nv.x); pk[1] = f2bf(nv.y); pk[2] = f2bf(nv.z); pk[3] = f2bf(nv.w);
                    *(bh4*)(xb + (size_t)gn * 128 + c0) = pk;
                }
            }
        }
    }
}

// ---------------- Output head: MFMA GEMM + in-register h-reduction ----------------
__global__ __launch_bounds__(256, 4) void out_head_mfma(
    const short* __restrict__ xb, const short* __restrict__ oW1T,
    const float* __restrict__ b1, const float* __restrict__ w2,
    const float* __restrict__ b2, float* __restrict__ sval) {
    __shared__ __align__(16) short Xs[64 * YP];
    __shared__ float red2[4][64];
    const int tid = threadIdx.x;
    const int n0 = blockIdx.x * 64;
    const int wv = tid >> 6;
    const int ln = tid & 63;
    const int lr = ln & 15;
    const int lq = ln >> 4;

    {
        int row = tid >> 2, p = tid & 3;
        int gn = n0 + row;
        if (gn < N_NODES) {
            const int4* xp = (const int4*)(xb + (size_t)gn * 128) + p * 4;
#pragma unroll
            for (int i = 0; i < 4; i++) *(int4*)(Xs + row * YP + (p * 4 + i) * 8) = xp[i];
        } else {
            int4 z4 = make_int4(0, 0, 0, 0);
#pragma unroll
            for (int i = 0; i < 4; i++) *(int4*)(Xs + row * YP + (p * 4 + i) * 8) = z4;
        }
    }
    __syncthreads();

    f32x4 acc[4][4];
#pragma unroll
    for (int a = 0; a < 4; a++)
#pragma unroll
        for (int b = 0; b < 4; b++) acc[a][b] = (f32x4)(0.f);

    const short* a_base = oW1T + (size_t)(wv * 64 + lr) * 128 + lq * 8;
#pragma unroll
    for (int ks = 0; ks < 128; ks += 32) {
        bh8 af[4], bf[4];
#pragma unroll
        for (int mt = 0; mt < 4; mt++) af[mt] = *(const bh8*)(a_base + mt * 16 * 128 + ks);
#pragma unroll
        for (int nt = 0; nt < 4; nt++)
            bf[nt] = *(const bh8*)(Xs + (nt * 16 + lr) * YP + ks + lq * 8);
#pragma unroll
        for (int mt = 0; mt < 4; mt++)
#pragma unroll
            for (int nt = 0; nt < 4; nt++)
                acc[mt][nt] = __builtin_amdgcn_mfma_f32_16x16x32_bf16(af[mt], bf[nt],
                                                                      acc[mt][nt], 0, 0, 0);
    }

    // per-thread partial over its 16 h values, for its 4 nodes
    float part[4] = {0.f, 0.f, 0.f, 0.f};
#pragma unroll
    for (int mt = 0; mt < 4; mt++) {
        int h0 = wv * 64 + mt * 16 + lq * 4;
        float4 bb = *(const float4*)(b1 + h0);
        float4 ww = *(const float4*)(w2 + h0);
#pragma unroll
        for (int nt = 0; nt < 4; nt++) {
            part[nt] += swish_f(acc[mt][nt][0] + bb.x) * ww.x
                      + swish_f(acc[mt][nt][1] + bb.y) * ww.y
                      + swish_f(acc[mt][nt][2] + bb.z) * ww.z
                      + swish_f(acc[mt][nt][3] + bb.w) * ww.w;
        }
    }
    // butterfly over lq (lanes lr, lr+16, lr+32, lr+48), then cross-wave via LDS
#pragma unroll
    for (int nt = 0; nt < 4; nt++) {
        float v = part[nt];
        v += __shfl_xor(v, 16, 64);
        v += __shfl_xor(v, 32, 64);
        if (lq == 0) red2[wv][nt * 16 + lr] = v;
    }
    __syncthreads();
    if (tid < 64) {
        int gn = n0 + tid;
        if (gn < N_NODES)
            sval[gn] = red2[0][tid] + red2[1][tid] + red2[2][tid] + red2[3][tid] + b2[0];
    }
}

__global__ void out_stage2(const float* __restrict__ sval, const int* __restrict__ batch,
                           float* __restrict__ partial) {
    __shared__ float part[N_GRAPHS];
    const int tid = threadIdx.x;
    if (tid < N_GRAPHS) part[tid] = 0.f;
    __syncthreads();
    const int per_block = (N_NODES + OB2 - 1) / OB2;
    const int start = blockIdx.x * per_block;
    const int end = min(start + per_block, N_NODES);
    const int per_thread = (per_block + 255) / 256;
    int s = start + tid * per_thread;
    int e = min(s + per_thread, end);
    if (s < e) {
        int g = batch[s];
        float a = sval[s];
        for (int n = s + 1; n < e; n++) {
            int gg = batch[n];
            float v = sval[n];
            if (gg != g) {
                atomicAdd(&part[g], a);
                a = v;
                g = gg;
            } else {
                a += v;
            }
        }
        atomicAdd(&part[g], a);
    }
    __syncthreads();
    if (tid < N_GRAPHS) partial[blockIdx.x * N_GRAPHS + tid] = part[tid];
}

__global__ void out_stage3(const float* __restrict__ partial, float* __restrict__ out) {
    int g = threadIdx.x;
    if (g >= N_GRAPHS) return;
    float s = 0.f;
    for (int b = 0; b < OB2; b++) s += partial[b * N_GRAPHS + g];
    out[g] = s;
}

extern "C" void kernel_launch(void* const* d_in, const int* in_sizes, int n_in,
                              void* d_out, int out_size, void* d_ws, size_t ws_size,
                              hipStream_t stream) {
    const float* positions = (const float*)d_in[0];
    const float* edge_shift = (const float*)d_in[1];
    const float* lattice = (const float*)d_in[2];
    const int* atomic_numbers = (const int*)d_in[3];
    const int* edge_index = (const int*)d_in[4];
    const int* batch = (const int*)d_in[5];
    const float* embed_w = (const float*)d_in[6];
    const float* edge_w1 = (const float*)d_in[7];
    const float* edge_b1 = (const float*)d_in[8];
    const float* edge_w2 = (const float*)d_in[9];
    const float* edge_b2 = (const float*)d_in[10];
    const float* node_w1 = (const float*)d_in[11];
    const float* node_b1 = (const float*)d_in[12];
    const float* node_w2 = (const float*)d_in[13];
    const float* node_b2 = (const float*)d_in[14];
    const float* out_w1 = (const float*)d_in[15];
    const float* out_b1 = (const float*)d_in[16];
    const float* out_w2 = (const float*)d_in[17];
    const float* out_b2 = (const float*)d_in[18];

    // workspace layout (every piece 16B-aligned; ~110 MB total)
    float* ws = (float*)d_ws;
    float* x = ws;                                   // N*128 f32
    short* xb = (short*)(x + (size_t)N_NODES * 128); // N*128 bf16
    short* aggb = xb + (size_t)N_NODES * 128;        // N*128 bf16
    short* ydb = aggb + (size_t)N_NODES * 128;       // N*256 bf16
    short* ysb = ydb + (size_t)N_NODES * 256;        // N*256 bf16
    short* WcT = ysb + (size_t)N_NODES * 256;        // 3*512*128 bf16
    short* eW2T = WcT + 3 * 512 * 128;               // 3*128*256
    short* nW1T = eW2T + 3 * 128 * 256;              // 3*256*256
    short* nW2T = nW1T + 3 * 256 * 256;              // 3*128*256
    short* oW1T = nW2T + 3 * 128 * 256;              // 256*128
    int* deg = (int*)(oW1T + 256 * 128);             // N
    int* fillc = deg + N_NODES;                      // N
    int* sc = fillc + N_NODES;                       // N
    int* bsum = sc + N_NODES;                        // 128
    int4* epack = (int4*)(bsum + 128);               // E * 16B (dst-sorted src,dst,d2)
    int* rowptr = (int*)(epack + N_EDGES);           // N+1
    float* sval = (float*)(rowptr + N_NODES + 4);    // N
    float* partial = sval + N_NODES;                 // OB2*N_GRAPHS

    (void)hipMemsetAsync(deg, 0, N_NODES * sizeof(int), stream);
    (void)hipMemsetAsync(fillc, 0, N_NODES * sizeof(int), stream);

    // weight transpose+cvt (tiny)
    {
        int tc = 3 * 512 * 128;
        cvt_wc_kernel<<<(tc + 255) / 256, 256, 0, stream>>>(edge_w1, WcT, tc);
        int t2 = 3 * 128 * 256;
        cvt_wT_kernel<<<(t2 + 255) / 256, 256, 0, stream>>>(edge_w2, eW2T, 256, 128, 256, t2);
        int t3 = 3 * 256 * 256;
        cvt_wT_kernel<<<(t3 + 255) / 256, 256, 0, stream>>>(node_w1, nW1T, 256, 256, 256, t3);
        cvt_wT_kernel<<<(t2 + 255) / 256, 256, 0, stream>>>(node_w2, nW2T, 256, 128, 256, t2);
        int t4 = 256 * 128;
        cvt_wT_kernel<<<(t4 + 255) / 256, 256, 0, stream>>>(out_w1, oW1T, 128, 256, 128, t4);
    }

    embed_kernel<<<(N_NODES * 128) / 256, 256, 0, stream>>>(embed_w, atomic_numbers, x, xb);

    // CSR counting sort by dst (d2 computed inline in fill)
    {
        int nscan = (N_NODES + SCAN_BS - 1) / SCAN_BS;
        hist_kernel<<<(N_EDGES + 255) / 256, 256, 0, stream>>>(edge_index, deg);
        scan1_kernel<<<nscan, SCAN_BS, 0, stream>>>(deg, sc, bsum, N_NODES);
        scan2_kernel<<<1, 128, 0, stream>>>(bsum, nscan);
        scan3_kernel<<<(N_NODES + SCAN_BS) / SCAN_BS + 1, SCAN_BS, 0, stream>>>(
            sc, deg, bsum, rowptr, N_NODES, N_EDGES);
        fill_kernel<<<(N_EDGES + 255) / 256, 256, 0, stream>>>(
            positions, edge_shift, lattice, edge_index, batch, rowptr, fillc, epack);
    }

    const int nblk = (N_NODES + 63) / 64;
    for (int l = 0; l < N_LAYERS; l++) {
        y_precompute<<<nblk * 2, 256, 0, stream>>>(
            xb, WcT + (size_t)l * 512 * 128, edge_b1 + (size_t)l * 256, ydb, ysb);
        edge_mlp_csr<<<N_NODES / DQ, 256, 0, stream>>>(
            ydb, ysb, edge_w1 + ((size_t)l * 257 + 256) * 256, epack, rowptr,
            eW2T + (size_t)l * 128 * 256, edge_b2 + (size_t)l * 128, aggb);
        node_mlp_mfma<<<nblk, 256, 0, stream>>>(
            x, xb, aggb,
            nW1T + (size_t)l * 256 * 256, node_b1 + (size_t)l * 256,
            nW2T + (size_t)l * 128 * 256, node_b2 + (size_t)l * 128);
    }
    out_head_mfma<<<nblk, 256, 0, stream>>>(xb, oW1T, out_b1, out_w2, out_b2, sval);
    out_stage2<<<OB2, 256, 0, stream>>>(sval, batch, partial);
    out_stage3<<<1, 64, 0, stream>>>(partial, (float*)d_out);
}

// Round 17
// 880.321 us; speedup vs baseline: 1.0454x; 1.0030x over previous
//
#include <hip/hip_runtime.h>
#include <hip/hip_bf16.h>

#define N_NODES 50000
#define N_EDGES 800000
#define N_GRAPHS 32
#define NODE_DIM 128
#define EDGE_DIM 128
#define HIDDEN 256
#define N_LAYERS 3

typedef __attribute__((ext_vector_type(8))) short bh8;   // 8 bf16 (4 VGPRs)
typedef __attribute__((ext_vector_type(4))) short bh4;   // 4 bf16 (8B)
typedef __attribute__((ext_vector_type(4))) float f32x4; // MFMA acc

#define MP 264  // M/H tile pitch (bf16)
#define YP 136  // X-tile pitch (bf16)
#define DQ 16   // dst nodes per edge-CSR block
#define YDP 264 // ydc LDS pitch (shorts)
#define WSP 36  // wsh pitch (floats)
#define SWP 40  // per-wave S-tile pitch (shorts): 80B rows -> 2-way-free b128 reads
#define STP 136 // epilogue agg staging pitch (shorts)
#define SCAN_BS 512
#define OB2 32  // out_stage2 blocks

// prep_all segment sizes
#define S_WC  (3 * 512 * 128)
#define S_EW2 (3 * 128 * 256)
#define S_NW1 (3 * 256 * 256)
#define S_NW2 (3 * 128 * 256)
#define S_OW1 (256 * 128)
#define S_EMB (N_NODES * 128)
#define S_TOT (S_WC + S_EW2 + S_NW1 + S_NW2 + S_OW1 + S_EMB)

// swish via hw rcp (avoids full-precision fp32 divide sequence)
__device__ __forceinline__ float swish_f(float v) {
    return v * __builtin_amdgcn_rcpf(1.0f + __expf(-v));
}

// round-half-up bf16 (2 int ops; differs from RNE only on exact ties)
__device__ __forceinline__ short f2bf(float f) {
    union { float f; unsigned u; } v;
    v.f = f;
    return (short)((v.u + 0x8000u) >> 16);
}

__device__ __forceinline__ float bf2f(short s) {
    union { unsigned u; float f; } v;
    v.u = ((unsigned)(unsigned short)s) << 16;
    return v.f;
}

// generic transpose-cvt body: out[l][h][k] = bf16(in[l][k][h]) for k<K_in else 0
__device__ __forceinline__ void cvt1(const float* __restrict__ in, short* __restrict__ out,
                                     int i, int K_in, int H, int K_pad) {
    int k = i % K_pad;
    int t = i / K_pad;
    int h = t % H;
    int l = t / H;
    out[i] = (k < K_in) ? f2bf(in[((size_t)l * K_in + k) * H + h]) : (short)0;
}

// ---------------- fused preamble: all weight cvts + embed in ONE dispatch ----------------
// Replaces 6 serial tiny launches; the 5 weight transposes ride concurrently with
// the 6.4M-element embed. Branches are block-uniform except at segment seams.
__global__ void prep_all(
    const float* __restrict__ edge_w1, short* __restrict__ WcT,
    const float* __restrict__ edge_w2, short* __restrict__ eW2T,
    const float* __restrict__ node_w1, short* __restrict__ nW1T,
    const float* __restrict__ node_w2, short* __restrict__ nW2T,
    const float* __restrict__ out_w1, short* __restrict__ oW1T,
    const float* __restrict__ emb, const int* __restrict__ z,
    float* __restrict__ x, short* __restrict__ xb) {
    int i = blockIdx.x * blockDim.x + threadIdx.x;
    if (i < S_WC) {
        // combined edge-W1 transpose: m<256 -> W1[l][k][m], m>=256 -> W1[l][128+k][m-256]
        int k = i & 127;
        int t = i >> 7;
        int m = t & 511;
        int l = t >> 9;
        size_t src;
        if (m < 256) src = ((size_t)l * 257 + k) * 256 + m;
        else src = ((size_t)l * 257 + 128 + k) * 256 + (m - 256);
        WcT[i] = f2bf(edge_w1[src]);
        return;
    }
    i -= S_WC;
    if (i < S_EW2) { cvt1(edge_w2, eW2T, i, 256, 128, 256); return; }
    i -= S_EW2;
    if (i < S_NW1) { cvt1(node_w1, nW1T, i, 256, 256, 256); return; }
    i -= S_NW1;
    if (i < S_NW2) { cvt1(node_w2, nW2T, i, 256, 128, 256); return; }
    i -= S_NW2;
    if (i < S_OW1) { cvt1(out_w1, oW1T, i, 128, 256, 128); return; }
    i -= S_OW1;
    if (i < S_EMB) {
        int n = i >> 7, c = i & 127;
        float v = emb[z[n] * 128 + c];
        x[i] = v;
        xb[i] = f2bf(v);
    }
}

// ---- CSR counting-sort build ----
__global__ void hist_kernel(const int* __restrict__ eidx, int* __restrict__ deg) {
    int e = blockIdx.x * blockDim.x + threadIdx.x;
    if (e >= N_EDGES) return;
    atomicAdd(&deg[eidx[N_EDGES + e]], 1);
}

__global__ void scan1_kernel(const int* __restrict__ deg, int* __restrict__ sc,
                             int* __restrict__ bsum, int n) {
    __shared__ int s[SCAN_BS];
    int i = blockIdx.x * SCAN_BS + threadIdx.x;
    int v = (i < n) ? deg[i] : 0;
    s[threadIdx.x] = v;
    __syncthreads();
    for (int off = 1; off < SCAN_BS; off <<= 1) {
        int t = (threadIdx.x >= off) ? s[threadIdx.x - off] : 0;
        __syncthreads();
        s[threadIdx.x] += t;
        __syncthreads();
    }
    if (i < n) sc[i] = s[threadIdx.x];
    if (threadIdx.x == SCAN_BS - 1) bsum[blockIdx.x] = s[SCAN_BS - 1];
}

__global__ void scan2_kernel(int* __restrict__ bsum, int nb) {  // 1 block, 128 threads
    __shared__ int s[128];
    int v = (threadIdx.x < nb) ? bsum[threadIdx.x] : 0;
    s[threadIdx.x] = v;
    __syncthreads();
    for (int off = 1; off < 128; off <<= 1) {
        int t = (threadIdx.x >= off) ? s[threadIdx.x - off] : 0;
        __syncthreads();
        s[threadIdx.x] += t;
        __syncthreads();
    }
    if (threadIdx.x < nb) bsum[threadIdx.x] = s[threadIdx.x];
}

__global__ void scan3_kernel(const int* __restrict__ sc, const int* __restrict__ deg,
                             const int* __restrict__ bsum, int* __restrict__ rowptr,
                             int n, int total) {
    int i = blockIdx.x * SCAN_BS + threadIdx.x;
    if (i > n) return;
    if (i == n) { rowptr[n] = total; return; }
    int off = (blockIdx.x > 0) ? bsum[blockIdx.x - 1] : 0;
    rowptr[i] = sc[i] - deg[i] + off;
}

// scatter into dst-sorted order, packing (src, dst, d2); d2 computed inline
__global__ void fill_kernel(const float* __restrict__ pos, const float* __restrict__ shift,
                            const float* __restrict__ lattice, const int* __restrict__ eidx,
                            const int* __restrict__ batch, const int* __restrict__ rowptr,
                            int* __restrict__ fillc, int4* __restrict__ epack) {
    int e = blockIdx.x * blockDim.x + threadIdx.x;
    if (e >= N_EDGES) return;
    int s = eidx[e];
    int d = eidx[N_EDGES + e];
    int b = batch[s];
    const float* lat = lattice + b * 9;
    float s0 = shift[e * 3 + 0], s1 = shift[e * 3 + 1], s2 = shift[e * 3 + 2];
    float acc = 0.f;
#pragma unroll
    for (int j = 0; j < 3; j++) {
        float v = pos[d * 3 + j] - pos[s * 3 + j] + s0 * lat[j] + s1 * lat[3 + j] + s2 * lat[6 + j];
        acc += v * v;
    }
    int p = rowptr[d] + atomicAdd(&fillc[d], 1);
    epack[p] = make_int4(s, d, __float_as_int(acc), 0);
}

// ---------------- per-layer node-level GEMM1 precompute ----------------
__global__ __launch_bounds__(256, 4) void y_precompute(
    const short* __restrict__ xb, const short* __restrict__ WcT,
    const float* __restrict__ b1, short* __restrict__ ydb, short* __restrict__ ysb) {
    __shared__ __align__(16) short B[64 * MP];  // X [64][YP] then Y [64][MP]
    const int tid = threadIdx.x;
    const int half = blockIdx.x & 1;
    const int n0 = (blockIdx.x >> 1) * 64;
    const int wv = tid >> 6;
    const int ln = tid & 63;
    const int lr = ln & 15;
    const int lq = ln >> 4;

    {
        int row = tid >> 2, p = tid & 3;
        int gn = n0 + row;
        if (gn < N_NODES) {
            const int4* xp = (const int4*)(xb + (size_t)gn * 128) + p * 4;
#pragma unroll
            for (int i = 0; i < 4; i++) *(int4*)(B + row * YP + (p * 4 + i) * 8) = xp[i];
        } else {
            int4 z4 = make_int4(0, 0, 0, 0);
#pragma unroll
            for (int i = 0; i < 4; i++) *(int4*)(B + row * YP + (p * 4 + i) * 8) = z4;
        }
    }
    __syncthreads();

    f32x4 acc[4][4];
#pragma unroll
    for (int a = 0; a < 4; a++)
#pragma unroll
        for (int b = 0; b < 4; b++) acc[a][b] = (f32x4)(0.f);

    const short* a_base = WcT + (size_t)(half * 256 + wv * 64 + lr) * 128 + lq * 8;
#pragma unroll
    for (int ks = 0; ks < 128; ks += 32) {
        bh8 af[4], bf[4];
#pragma unroll
        for (int mt = 0; mt < 4; mt++) af[mt] = *(const bh8*)(a_base + mt * 16 * 128 + ks);
#pragma unroll
        for (int nt = 0; nt < 4; nt++)
            bf[nt] = *(const bh8*)(B + (nt * 16 + lr) * YP + ks + lq * 8);
#pragma unroll
        for (int mt = 0; mt < 4; mt++)
#pragma unroll
            for (int nt = 0; nt < 4; nt++)
                acc[mt][nt] = __builtin_amdgcn_mfma_f32_16x16x32_bf16(af[mt], bf[nt],
                                                                      acc[mt][nt], 0, 0, 0);
    }
    __syncthreads();   // done reading X -> B becomes Y [64][MP]

#pragma unroll
    for (int mt = 0; mt < 4; mt++) {
        int h0 = wv * 64 + mt * 16 + lq * 4;
        float4 bb = half ? make_float4(0.f, 0.f, 0.f, 0.f) : *(const float4*)(b1 + h0);
#pragma unroll
        for (int nt = 0; nt < 4; nt++) {
            bh4 pk;
            pk[0] = f2bf(acc[mt][nt][0] + bb.x);
            pk[1] = f2bf(acc[mt][nt][1] + bb.y);
            pk[2] = f2bf(acc[mt][nt][2] + bb.z);
            pk[3] = f2bf(acc[mt][nt][3] + bb.w);
            *(bh4*)(B + (nt * 16 + lr) * MP + h0) = pk;
        }
    }
    __syncthreads();

    // coalesced copy: instr i writes 64 consecutive int4 (1KB contiguous)
    short* outp = half ? ysb : ydb;
    int4* og = (int4*)(outp + (size_t)n0 * 256);
#pragma unroll
    for (int i = 0; i < 8; i++) {
        int f = i * 256 + tid;             // flat int4 index over [64][256]
        int row = f >> 5;
        if (n0 + row < N_NODES)
            og[f] = *(const int4*)(B + row * MP + (f & 31) * 8);
    }
}

// ---------------- Edge MLP, CSR dst-centric, MFMA segment aggregation ----------------
// r12 form (best verified: 177.5us, VGPR 84, zero spill). (256,3) releases the
// 64-VGPR clamp; usage 65..128 VGPRs keeps 4 waves/SIMD -> no occupancy loss.
__global__ __launch_bounds__(256, 3) void edge_mlp_csr(
    const short* __restrict__ ydb, const short* __restrict__ ysb,
    const float* __restrict__ w1c,   // [256] f32: W1 row 256 (the d2 row)
    const int4* __restrict__ epack,  // dst-sorted (src, dst, d2)
    const int* __restrict__ rowptr,
    const short* __restrict__ W2T,   // [128][256] bf16
    const float* __restrict__ b2,
    short* __restrict__ aggb) {
    __shared__ __align__(16) short MB[32 * MP];     // 16896B: M tile
    __shared__ __align__(16) short Stw[4 * 32 * SWP]; // 10240B: per-wave S tiles / agg staging
    __shared__ __align__(16) short ydc[DQ * YDP];   // 8448B
    __shared__ __align__(16) float wsh[8 * WSP];    // 1152B
    __shared__ int s_dl[32];
    const int tid = threadIdx.x;
    const int n0 = blockIdx.x * DQ;
    const int wv = tid >> 6;
    const int ln = tid & 63;
    const int lr = ln & 15;
    const int lq = ln >> 4;
    const int el = tid >> 3;
    const int p = tid & 7;

    const int estart = rowptr[n0];
    const int eend = rowptr[n0 + DQ];

    // ---- phase 0: stage yd rows (coalesced), w1c -> wsh ----
    {
        const int4* src = (const int4*)(ydb + (size_t)n0 * 256);  // 512 int4 contiguous
        int4* dst = (int4*)ydc;
#pragma unroll
        for (int i = 0; i < 2; i++) {
            int f = tid + i * 256;
            dst[(f >> 5) * 33 + (f & 31)] = src[f];   // YDP=264 shorts = 33 int4
        }
        wsh[(tid >> 5) * WSP + (tid & 31)] = w1c[tid];
    }
    __syncthreads();

    f32x4 acc2[2];
    acc2[0] = (f32x4)(0.f);
    acc2[1] = (f32x4)(0.f);
    short* Sw = Stw + wv * 32 * SWP;   // wave-private [32 ch][SWP] bf16

    const int nch = (eend - estart + 31) >> 5;
    for (int ch = 0; ch < nch; ch++) {
        const int e0 = estart + ch * 32;

        // ---- stage A: gather ys[src] + ydc[dl] + d2*wsh -> swish -> M (8 thr/edge) ----
        {
            int e = e0 + el;
            bool valid = e < eend;
            int s = 0, dl = -1;
            float d2v = 0.f;
            if (valid) {
                int4 ep = epack[e];
                s = ep.x;
                dl = ep.y - n0;
                d2v = __int_as_float(ep.z);
            }
            if (p == 0) s_dl[el] = dl;
            if (valid) {
                const int4* ys = (const int4*)(ysb + (size_t)s * 256) + p * 4;
                const short* yl = ydc + dl * YDP + p * 32;
                const float* wl = wsh + p * WSP;
#pragma unroll
                for (int h = 0; h < 2; h++) {
                    int4 bv0 = ys[h * 2];
                    int4 bv1 = ys[h * 2 + 1];
#pragma unroll
                    for (int qq = 0; qq < 2; qq++) {
                        int q = h * 2 + qq;
                        union { int4 v; short s2[8]; } b, m;
                        b.v = qq ? bv1 : bv0;
                        bh8 av = *(const bh8*)(yl + q * 8);
                        float4 w0 = *(const float4*)(wl + q * 8);
                        float4 w1 = *(const float4*)(wl + q * 8 + 4);
                        m.s2[0] = f2bf(swish_f(bf2f(av[0]) + bf2f(b.s2[0]) + d2v * w0.x));
                        m.s2[1] = f2bf(swish_f(bf2f(av[1]) + bf2f(b.s2[1]) + d2v * w0.y));
                        m.s2[2] = f2bf(swish_f(bf2f(av[2]) + bf2f(b.s2[2]) + d2v * w0.z));
                        m.s2[3] = f2bf(swish_f(bf2f(av[3]) + bf2f(b.s2[3]) + d2v * w0.w));
                        m.s2[4] = f2bf(swish_f(bf2f(av[4]) + bf2f(b.s2[4]) + d2v * w1.x));
                        m.s2[5] = f2bf(swish_f(bf2f(av[5]) + bf2f(b.s2[5]) + d2v * w1.y));
                        m.s2[6] = f2bf(swish_f(bf2f(av[6]) + bf2f(b.s2[6]) + d2v * w1.z));
                        m.s2[7] = f2bf(swish_f(bf2f(av[7]) + bf2f(b.s2[7]) + d2v * w1.w));
                        *(int4*)(MB + el * MP + p * 32 + q * 8) = m.v;
                    }
                }
            } else {
                int4 z4 = make_int4(0, 0, 0, 0);
#pragma unroll
                for (int q = 0; q < 4; q++) *(int4*)(MB + el * MP + p * 32 + q * 8) = z4;
            }
        }
        __syncthreads();   // (A) M + s_dl ready

        // ---- GEMM2: 128 ch x 32 edges, each wave 32 ch; S -> wave-private bf16 tile ----
        {
            f32x4 acc[2][2];
#pragma unroll
            for (int a = 0; a < 2; a++)
#pragma unroll
                for (int b = 0; b < 2; b++) acc[a][b] = (f32x4)(0.f);

            const short* a_base = W2T + (size_t)(wv * 32 + lr) * 256 + lq * 8;
            for (int ks = 0; ks < 256; ks += 32) {
                bh8 af[2], bf[2];
#pragma unroll
                for (int mt = 0; mt < 2; mt++) af[mt] = *(const bh8*)(a_base + mt * 16 * 256 + ks);
#pragma unroll
                for (int nt = 0; nt < 2; nt++)
                    bf[nt] = *(const bh8*)(MB + (nt * 16 + lr) * MP + ks + lq * 8);
#pragma unroll
                for (int mt = 0; mt < 2; mt++)
#pragma unroll
                    for (int nt = 0; nt < 2; nt++)
                        acc[mt][nt] = __builtin_amdgcn_mfma_f32_16x16x32_bf16(af[mt], bf[nt],
                                                                              acc[mt][nt], 0, 0, 0);
            }
            // swish2 + bf16 -> Sw[row=ch (32), col=e (32)]  (wave-private, no barrier)
#pragma unroll
            for (int mt = 0; mt < 2; mt++) {
                int r0 = mt * 16 + lq * 4;
                float4 bb = *(const float4*)(b2 + wv * 32 + r0);
#pragma unroll
                for (int nt = 0; nt < 2; nt++) {
                    int e = nt * 16 + lr;
                    Sw[(r0 + 0) * SWP + e] = f2bf(swish_f(acc[mt][nt][0] + bb.x));
                    Sw[(r0 + 1) * SWP + e] = f2bf(swish_f(acc[mt][nt][1] + bb.y));
                    Sw[(r0 + 2) * SWP + e] = f2bf(swish_f(acc[mt][nt][2] + bb.z));
                    Sw[(r0 + 3) * SWP + e] = f2bf(swish_f(acc[mt][nt][3] + bb.w));
                }
            }
        }

        // ---- seg-MFMA aggregation: acc2[mt] += Seg @ S  ----
        {
            bh8 af;
#pragma unroll
            for (int j = 0; j < 8; j++)
                af[j] = (s_dl[lq * 8 + j] == lr) ? (short)0x3F80 : (short)0;
#pragma unroll
            for (int mt = 0; mt < 2; mt++) {
                bh8 bfv = *(const bh8*)(Sw + (mt * 16 + lr) * SWP + lq * 8);
                acc2[mt] = __builtin_amdgcn_mfma_f32_16x16x32_bf16(af, bfv, acc2[mt], 0, 0, 0);
            }
        }
        __syncthreads();   // (B) M-reads + s_dl-reads done before next stageA
    }

    // ---- epilogue: acc2 (C layout: row dl=(lq*4+j), col ch=lr) -> LDS -> coalesced bf16 ----
#pragma unroll
    for (int mt = 0; mt < 2; mt++)
#pragma unroll
        for (int j = 0; j < 4; j++)
            Stw[(lq * 4 + j) * STP + wv * 32 + mt * 16 + lr] = f2bf(acc2[mt][j]);
    __syncthreads();
    {
        int row = tid >> 4, c16 = tid & 15;
        *(int4*)(aggb + ((size_t)(n0 + row)) * 128 + c16 * 8) =
            *(const int4*)(Stw + row * STP + c16 * 8);
    }
}

// ---------------- Node MLP (MFMA, single LDS buffer, 4 blocks/CU) ----------------
__global__ __launch_bounds__(256, 4) void node_mlp_mfma(
    float* __restrict__ x, short* __restrict__ xb, const short* __restrict__ aggb,
    const short* __restrict__ W1T, const float* __restrict__ b1,
    const short* __restrict__ W2T, const float* __restrict__ b2) {
    __shared__ __align__(16) short X[64 * MP];
    const int tid = threadIdx.x;
    const int n0 = blockIdx.x * 64;
    const int wv = tid >> 6;
    const int ln = tid & 63;
    const int lr = ln & 15;
    const int lq = ln >> 4;

    {
        int row = tid >> 2, p = tid & 3;
        int gn = n0 + row;
        if (gn < N_NODES) {
            const int4* xp = (const int4*)(xb + (size_t)gn * 128);
            const int4* ap = (const int4*)(aggb + (size_t)gn * 128);
#pragma unroll
            for (int q = 0; q < 4; q++) {
                int c = p * 4 + q;
                *(int4*)(X + row * MP + c * 8) = xp[c];
                *(int4*)(X + row * MP + 128 + c * 8) = ap[c];
            }
        } else {
            int4 z4 = make_int4(0, 0, 0, 0);
#pragma unroll
            for (int q = 0; q < 8; q++) *(int4*)(X + row * MP + (p * 8 + q) * 8) = z4;
        }
    }
    __syncthreads();

    bh4 hv[4][4];
    {
        f32x4 acc[4][4];
#pragma unroll
        for (int a = 0; a < 4; a++)
#pragma unroll
            for (int b = 0; b < 4; b++) acc[a][b] = (f32x4)(0.f);

        const short* a_base = W1T + (size_t)(wv * 64 + lr) * 256 + lq * 8;
        for (int ks = 0; ks < 256; ks += 32) {
            bh8 af[4], bf[4];
#pragma unroll
            for (int mt = 0; mt < 4; mt++) af[mt] = *(const bh8*)(a_base + mt * 16 * 256 + ks);
#pragma unroll
            for (int nt = 0; nt < 4; nt++)
                bf[nt] = *(const bh8*)(X + (nt * 16 + lr) * MP + ks + lq * 8);
#pragma unroll
            for (int mt = 0; mt < 4; mt++)
#pragma unroll
                for (int nt = 0; nt < 4; nt++)
                    acc[mt][nt] = __builtin_amdgcn_mfma_f32_16x16x32_bf16(af[mt], bf[nt],
                                                                          acc[mt][nt], 0, 0, 0);
        }
#pragma unroll
        for (int mt = 0; mt < 4; mt++) {
            int h0 = wv * 64 + mt * 16 + lq * 4;
            float4 bb = *(const float4*)(b1 + h0);
#pragma unroll
            for (int nt = 0; nt < 4; nt++) {
                hv[mt][nt][0] = f2bf(swish_f(acc[mt][nt][0] + bb.x));
                hv[mt][nt][1] = f2bf(swish_f(acc[mt][nt][1] + bb.y));
                hv[mt][nt][2] = f2bf(swish_f(acc[mt][nt][2] + bb.z));
                hv[mt][nt][3] = f2bf(swish_f(acc[mt][nt][3] + bb.w));
            }
        }
    }
    __syncthreads();   // done reading A -> buffer becomes H

#pragma unroll
    for (int mt = 0; mt < 4; mt++) {
        int h0 = wv * 64 + mt * 16 + lq * 4;
#pragma unroll
        for (int nt = 0; nt < 4; nt++) {
            int e = nt * 16 + lr;
            *(bh4*)(X + e * MP + h0) = hv[mt][nt];
        }
    }
    __syncthreads();

    {
        f32x4 acc[2][4];
#pragma unroll
        for (int a = 0; a < 2; a++)
#pragma unroll
            for (int b = 0; b < 4; b++) acc[a][b] = (f32x4)(0.f);

        const short* a_base = W2T + (size_t)(wv * 32 + lr) * 256 + lq * 8;
        for (int ks = 0; ks < 256; ks += 32) {
            bh8 af[2], bf[4];
#pragma unroll
            for (int mt = 0; mt < 2; mt++) af[mt] = *(const bh8*)(a_base + mt * 16 * 256 + ks);
#pragma unroll
            for (int nt = 0; nt < 4; nt++)
                bf[nt] = *(const bh8*)(X + (nt * 16 + lr) * MP + ks + lq * 8);
#pragma unroll
            for (int mt = 0; mt < 2; mt++)
#pragma unroll
                for (int nt = 0; nt < 4; nt++)
                    acc[mt][nt] = __builtin_amdgcn_mfma_f32_16x16x32_bf16(af[mt], bf[nt],
                                                                          acc[mt][nt], 0, 0, 0);
        }
#pragma unroll
        for (int mt = 0; mt < 2; mt++) {
            int c0 = wv * 32 + mt * 16 + lq * 4;
            float4 bb = *(const float4*)(b2 + c0);
#pragma unroll
            for (int nt = 0; nt < 4; nt++) {
                int nl = nt * 16 + lr;
                int gn = n0 + nl;
                if (gn < N_NODES) {
                    float4 xv = *(const float4*)(x + (size_t)gn * 128 + c0);
                    float4 nv;
                    nv.x = xv.x + acc[mt][nt][0] + bb.x;
                    nv.y = xv.y + acc[mt][nt][1] + bb.y;
                    nv.z = xv.z + acc[mt][nt][2] + bb.z;
                    nv.w = xv.w + acc[mt][nt][3] + bb.w;
                    *(float4*)(x + (size_t)gn * 128 + c0) = nv;
                    bh4 pk;
                    pk[0] = f2bf(nv.x); pk[1] = f2bf(nv.y); pk[2] = f2bf(nv.z); pk[3] = f2bf(nv.w);
                    *(bh4*)(xb + (size_t)gn * 128 + c0) = pk;
                }
            }
        }
    }
}

// ---------------- Output head: MFMA GEMM + in-register h-reduction ----------------
__global__ __launch_bounds__(256, 4) void out_head_mfma(
    const short* __restrict__ xb, const short* __restrict__ oW1T,
    const float* __restrict__ b1, const float* __restrict__ w2,
    const float* __restrict__ b2, float* __restrict__ sval) {
    __shared__ __align__(16) short Xs[64 * YP];
    __shared__ float red2[4][64];
    const int tid = threadIdx.x;
    const int n0 = blockIdx.x * 64;
    const int wv = tid >> 6;
    const int ln = tid & 63;
    const int lr = ln & 15;
    const int lq = ln >> 4;

    {
        int row = tid >> 2, p = tid & 3;
        int gn = n0 + row;
        if (gn < N_NODES) {
            const int4* xp = (const int4*)(xb + (size_t)gn * 128) + p * 4;
#pragma unroll
            for (int i = 0; i < 4; i++) *(int4*)(Xs + row * YP + (p * 4 + i) * 8) = xp[i];
        } else {
            int4 z4 = make_int4(0, 0, 0, 0);
#pragma unroll
            for (int i = 0; i < 4; i++) *(int4*)(Xs + row * YP + (p * 4 + i) * 8) = z4;
        }
    }
    __syncthreads();

    f32x4 acc[4][4];
#pragma unroll
    for (int a = 0; a < 4; a++)
#pragma unroll
        for (int b = 0; b < 4; b++) acc[a][b] = (f32x4)(0.f);

    const short* a_base = oW1T + (size_t)(wv * 64 + lr) * 128 + lq * 8;
#pragma unroll
    for (int ks = 0; ks < 128; ks += 32) {
        bh8 af[4], bf[4];
#pragma unroll
        for (int mt = 0; mt < 4; mt++) af[mt] = *(const bh8*)(a_base + mt * 16 * 128 + ks);
#pragma unroll
        for (int nt = 0; nt < 4; nt++)
            bf[nt] = *(const bh8*)(Xs + (nt * 16 + lr) * YP + ks + lq * 8);
#pragma unroll
        for (int mt = 0; mt < 4; mt++)
#pragma unroll
            for (int nt = 0; nt < 4; nt++)
                acc[mt][nt] = __builtin_amdgcn_mfma_f32_16x16x32_bf16(af[mt], bf[nt],
                                                                      acc[mt][nt], 0, 0, 0);
    }

    // per-thread partial over its 16 h values, for its 4 nodes
    float part[4] = {0.f, 0.f, 0.f, 0.f};
#pragma unroll
    for (int mt = 0; mt < 4; mt++) {
        int h0 = wv * 64 + mt * 16 + lq * 4;
        float4 bb = *(const float4*)(b1 + h0);
        float4 ww = *(const float4*)(w2 + h0);
#pragma unroll
        for (int nt = 0; nt < 4; nt++) {
            part[nt] += swish_f(acc[mt][nt][0] + bb.x) * ww.x
                      + swish_f(acc[mt][nt][1] + bb.y) * ww.y
                      + swish_f(acc[mt][nt][2] + bb.z) * ww.z
                      + swish_f(acc[mt][nt][3] + bb.w) * ww.w;
        }
    }
    // butterfly over lq (lanes lr, lr+16, lr+32, lr+48), then cross-wave via LDS
#pragma unroll
    for (int nt = 0; nt < 4; nt++) {
        float v = part[nt];
        v += __shfl_xor(v, 16, 64);
        v += __shfl_xor(v, 32, 64);
        if (lq == 0) red2[wv][nt * 16 + lr] = v;
    }
    __syncthreads();
    if (tid < 64) {
        int gn = n0 + tid;
        if (gn < N_NODES)
            sval[gn] = red2[0][tid] + red2[1][tid] + red2[2][tid] + red2[3][tid] + b2[0];
    }
}

__global__ void out_stage2(const float* __restrict__ sval, const int* __restrict__ batch,
                           float* __restrict__ partial) {
    __shared__ float part[N_GRAPHS];
    const int tid = threadIdx.x;
    if (tid < N_GRAPHS) part[tid] = 0.f;
    __syncthreads();
    const int per_block = (N_NODES + OB2 - 1) / OB2;
    const int start = blockIdx.x * per_block;
    const int end = min(start + per_block, N_NODES);
    const int per_thread = (per_block + 255) / 256;
    int s = start + tid * per_thread;
    int e = min(s + per_thread, end);
    if (s < e) {
        int g = batch[s];
        float a = sval[s];
        for (int n = s + 1; n < e; n++) {
            int gg = batch[n];
            float v = sval[n];
            if (gg != g) {
                atomicAdd(&part[g], a);
                a = v;
                g = gg;
            } else {
                a += v;
            }
        }
        atomicAdd(&part[g], a);
    }
    __syncthreads();
    if (tid < N_GRAPHS) partial[blockIdx.x * N_GRAPHS + tid] = part[tid];
}

__global__ void out_stage3(const float* __restrict__ partial, float* __restrict__ out) {
    int g = threadIdx.x;
    if (g >= N_GRAPHS) return;
    float s = 0.f;
    for (int b = 0; b < OB2; b++) s += partial[b * N_GRAPHS + g];
    out[g] = s;
}

extern "C" void kernel_launch(void* const* d_in, const int* in_sizes, int n_in,
                              void* d_out, int out_size, void* d_ws, size_t ws_size,
                              hipStream_t stream) {
    const float* positions = (const float*)d_in[0];
    const float* edge_shift = (const float*)d_in[1];
    const float* lattice = (const float*)d_in[2];
    const int* atomic_numbers = (const int*)d_in[3];
    const int* edge_index = (const int*)d_in[4];
    const int* batch = (const int*)d_in[5];
    const float* embed_w = (const float*)d_in[6];
    const float* edge_w1 = (const float*)d_in[7];
    const float* edge_b1 = (const float*)d_in[8];
    const float* edge_w2 = (const float*)d_in[9];
    const float* edge_b2 = (const float*)d_in[10];
    const float* node_w1 = (const float*)d_in[11];
    const float* node_b1 = (const float*)d_in[12];
    const float* node_w2 = (const float*)d_in[13];
    const float* node_b2 = (const float*)d_in[14];
    const float* out_w1 = (const float*)d_in[15];
    const float* out_b1 = (const float*)d_in[16];
    const float* out_w2 = (const float*)d_in[17];
    const float* out_b2 = (const float*)d_in[18];

    // workspace layout (every piece 16B-aligned; ~110 MB total)
    float* ws = (float*)d_ws;
    float* x = ws;                                   // N*128 f32
    short* xb = (short*)(x + (size_t)N_NODES * 128); // N*128 bf16
    short* aggb = xb + (size_t)N_NODES * 128;        // N*128 bf16
    short* ydb = aggb + (size_t)N_NODES * 128;       // N*256 bf16
    short* ysb = ydb + (size_t)N_NODES * 256;        // N*256 bf16
    short* WcT = ysb + (size_t)N_NODES * 256;        // 3*512*128 bf16
    short* eW2T = WcT + 3 * 512 * 128;               // 3*128*256
    short* nW1T = eW2T + 3 * 128 * 256;              // 3*256*256
    short* nW2T = nW1T + 3 * 256 * 256;              // 3*128*256
    short* oW1T = nW2T + 3 * 128 * 256;              // 256*128
    int* deg = (int*)(oW1T + 256 * 128);             // N
    int* fillc = deg + N_NODES;                      // N
    int* sc = fillc + N_NODES;                       // N
    int* bsum = sc + N_NODES;                        // 128
    int4* epack = (int4*)(bsum + 128);               // E * 16B (dst-sorted src,dst,d2)
    int* rowptr = (int*)(epack + N_EDGES);           // N+1
    float* sval = (float*)(rowptr + N_NODES + 4);    // N
    float* partial = sval + N_NODES;                 // OB2*N_GRAPHS

    (void)hipMemsetAsync(deg, 0, N_NODES * sizeof(int), stream);
    (void)hipMemsetAsync(fillc, 0, N_NODES * sizeof(int), stream);

    // fused preamble: all weight transposes + embed in one dispatch
    prep_all<<<(S_TOT + 255) / 256, 256, 0, stream>>>(
        edge_w1, WcT, edge_w2, eW2T, node_w1, nW1T, node_w2, nW2T,
        out_w1, oW1T, embed_w, atomic_numbers, x, xb);

    // CSR counting sort by dst (d2 computed inline in fill)
    {
        int nscan = (N_NODES + SCAN_BS - 1) / SCAN_BS;
        hist_kernel<<<(N_EDGES + 255) / 256, 256, 0, stream>>>(edge_index, deg);
        scan1_kernel<<<nscan, SCAN_BS, 0, stream>>>(deg, sc, bsum, N_NODES);
        scan2_kernel<<<1, 128, 0, stream>>>(bsum, nscan);
        scan3_kernel<<<(N_NODES + SCAN_BS) / SCAN_BS + 1, SCAN_BS, 0, stream>>>(
            sc, deg, bsum, rowptr, N_NODES, N_EDGES);
        fill_kernel<<<(N_EDGES + 255) / 256, 256, 0, stream>>>(
            positions, edge_shift, lattice, edge_index, batch, rowptr, fillc, epack);
    }

    const int nblk = (N_NODES + 63) / 64;
    for (int l = 0; l < N_LAYERS; l++) {
        y_precompute<<<nblk * 2, 256, 0, stream>>>(
            xb, WcT + (size_t)l * 512 * 128, edge_b1 + (size_t)l * 256, ydb, ysb);
        edge_mlp_csr<<<N_NODES / DQ, 256, 0, stream>>>(
            ydb, ysb, edge_w1 + ((size_t)l * 257 + 256) * 256, epack, rowptr,
            eW2T + (size_t)l * 128 * 256, edge_b2 + (size_t)l * 128, aggb);
        node_mlp_mfma<<<nblk, 256, 0, stream>>>(
            x, xb, aggb,
            nW1T + (size_t)l * 256 * 256, node_b1 + (size_t)l * 256,
            nW2T + (size_t)l * 128 * 256, node_b2 + (size_t)l * 128);
    }
    out_head_mfma<<<nblk, 256, 0, stream>>>(xb, oW1T, out_b1, out_w2, out_b2, sval);
    out_stage2<<<OB2, 256, 0, stream>>>(sval, batch, partial);
    out_stage3<<<1, 64, 0, stream>>>(partial, (float*)d_out);
}